// Round 5
// baseline (587.737 us; speedup 1.0000x reference)
//
#include <hip/hip_runtime.h>

#define N_CAT   100000
#define N_USERS 50000
#define DIM     64
#define N_RELM1 15
#define E_EDGES 1500000
#define NNZ_E   1500000
#define HR      12500   // N_CAT/8
#define UR      6250    // N_USERS/8

#define NTL(p) __builtin_nontemporal_load(p)

// K1: normsq[n][r] = sum_d (cat[n][d] * w[r][d])^2  — one wave per node
__global__ void normsq_kernel(const float* __restrict__ cat,
                              const float* __restrict__ weight,
                              float* __restrict__ normsq) {
    int gtid = blockIdx.x * blockDim.x + threadIdx.x;
    int node = gtid >> 6;
    int lane = threadIdx.x & 63;
    if (node >= N_CAT) return;
    float c = cat[node * DIM + lane];
    float myval = 0.f;
#pragma unroll
    for (int r = 0; r < N_RELM1; ++r) {
        float t = c * weight[r * DIM + lane];
        float s = t * t;
#pragma unroll
        for (int off = 1; off < 64; off <<= 1)
            s += __shfl_xor(s, off, 64);
        if (lane == r) myval = s;
    }
    if (lane < N_RELM1) normsq[node * N_RELM1 + lane] = myval;
}

// K2: XCD-grouped histograms — group g only counts its own 1/8 id-range
__global__ void hist_kernel(const int* __restrict__ head, const int* __restrict__ iu,
                            int* __restrict__ hcnt, int* __restrict__ ucnt) {
    int g  = blockIdx.x & 7;
    int lb = blockIdx.x >> 3;
    int stride = (gridDim.x >> 3) * blockDim.x;
    for (int e = lb * blockDim.x + threadIdx.x; e < E_EDGES; e += stride) {
        int h = NTL(&head[e]);
        if (h / HR == g) atomicAdd(&hcnt[h], 1);
        int u = NTL(&iu[e]);
        if (u / UR == g) atomicAdd(&ucnt[u], 1);
    }
}

// K3a: per-1024-block exclusive scan; block totals out
__global__ void scanA_kernel(const int* __restrict__ hcnt, int* __restrict__ hoff,
                             const int* __restrict__ ucnt, int* __restrict__ uoff,
                             int* __restrict__ hbtot, int* __restrict__ ubtot) {
    __shared__ int wsum[16];
    int bid = blockIdx.x;
    const int* src; int* dst; int* btot; int n; int base;
    if (bid < 98) { src = hcnt; dst = hoff; btot = hbtot + bid; n = N_CAT;  base = bid * 1024; }
    else { int b = bid - 98; src = ucnt; dst = uoff; btot = ubtot + b; n = N_USERS; base = b * 1024; }
    int i = base + threadIdx.x;
    int lane = threadIdx.x & 63, wid = threadIdx.x >> 6;
    int v = (i < n) ? src[i] : 0;
    int s = v;
#pragma unroll
    for (int d = 1; d < 64; d <<= 1) {
        int t = __shfl_up(s, d, 64);
        if (lane >= d) s += t;
    }
    if (lane == 63) wsum[wid] = s;
    __syncthreads();
    int wpre = 0, tot = 0;
#pragma unroll
    for (int w = 0; w < 16; ++w) {
        int x = wsum[w];
        if (w < wid) wpre += x;
        tot += x;
    }
    if (i < n) dst[i] = wpre + s - v;
    if (threadIdx.x == 0) *btot = tot;
}

// K3b: exclusive scan of block totals (block 0: 98 cat totals, block 1: 49 user totals)
__global__ void scanB_kernel(int* __restrict__ hbtot, int* __restrict__ ubtot) {
    int* b = (blockIdx.x == 0) ? hbtot : ubtot;
    int n  = (blockIdx.x == 0) ? 98 : 49;
    __shared__ int w0;
    int lane = threadIdx.x & 63, wid = threadIdx.x >> 6;
    int i = threadIdx.x;
    int v = (i < n) ? b[i] : 0;
    int s = v;
#pragma unroll
    for (int d = 1; d < 64; d <<= 1) {
        int t = __shfl_up(s, d, 64);
        if (lane >= d) s += t;
    }
    if (wid == 0 && lane == 63) w0 = s;
    __syncthreads();
    int add = (wid == 1) ? w0 : 0;
    if (i < n) b[i] = add + s - v;
}

// K3c: add block offsets, materialize cursors (reusing cnt arrays), write totals
__global__ void scanC_kernel(int* __restrict__ hoff, int* __restrict__ uoff,
                             const int* __restrict__ hbtot, const int* __restrict__ ubtot,
                             int* __restrict__ hcur, int* __restrict__ ucur) {
    int i = blockIdx.x * 1024 + threadIdx.x;
    if (i < N_CAT) {
        int v = hoff[i] + hbtot[i >> 10];
        hoff[i] = v; hcur[i] = v;
    } else if (i < N_CAT + N_USERS) {
        int j = i - N_CAT;
        int v = uoff[j] + ubtot[j >> 10];
        uoff[j] = v; ucur[j] = v;
    }
    if (i == 0) { hoff[N_CAT] = E_EDGES; uoff[N_USERS] = NNZ_E; }
}

// K4: XCD-grouped scatter with packed payloads; nt loads keep the edge streams
// from evicting the partially-filled destination lines out of this XCD's L2
__global__ void scatter_kernel(const int* __restrict__ head, const int* __restrict__ tail,
                               const int* __restrict__ etype,
                               const int* __restrict__ iu, const int* __restrict__ ic,
                               const float* __restrict__ ival,
                               int* __restrict__ hcur, int* __restrict__ ucur,
                               int* __restrict__ esorted, long long* __restrict__ nsorted2) {
    int g  = blockIdx.x & 7;
    int lb = blockIdx.x >> 3;
    int stride = (gridDim.x >> 3) * blockDim.x;
    for (int e = lb * blockDim.x + threadIdx.x; e < E_EDGES; e += stride) {
        int h = NTL(&head[e]);
        if (h / HR == g) {
            int p = atomicAdd(&hcur[h], 1);
            esorted[p] = (NTL(&tail[e]) << 4) | (NTL(&etype[e]) - 1);
        }
        int u = NTL(&iu[e]);
        if (u / UR == g) {
            int p = atomicAdd(&ucur[u], 1);
            unsigned int lo = (unsigned int)NTL(&ic[e]);
            unsigned int hi = (unsigned int)__float_as_uint(NTL(&ival[e]));
            nsorted2[p] = (long long)(((unsigned long long)hi << 32) | lo);
        }
    }
}

// K5: per-head online-softmax aggregation — swizzled so head-range g runs on XCD g
__global__ void cat_agg_kernel(const int* __restrict__ esorted,
                               const int* __restrict__ hoff,
                               const float* __restrict__ normsq,
                               const float* __restrict__ cat,
                               const float* __restrict__ weight,
                               float* __restrict__ catagg) {
    int g = blockIdx.x & 7, lb = blockIdx.x >> 3;
    int wid = threadIdx.x >> 6, lane = threadIdx.x & 63;
    int h = g * HR + lb * 4 + wid;
    int s0 = hoff[h], s1 = hoff[h + 1];
    float acc = 0.f, Z = 0.f, m = -1e30f;
    for (int base = s0; base < s1; base += 64) {
        int cn = min(64, s1 - base);
        float att = -1e30f;
        int pk = 0;
        if (lane < cn) {
            pk = NTL(&esorted[base + lane]);
            int t = pk >> 4, r = pk & 15;
            att = normsq[h * N_RELM1 + r] * normsq[(size_t)t * N_RELM1 + r];
        }
        float cm = att;
#pragma unroll
        for (int off = 1; off < 64; off <<= 1)
            cm = fmaxf(cm, __shfl_xor(cm, off, 64));
        float nm = fmaxf(m, cm);
        float scale = expf(m - nm);
        acc *= scale; Z *= scale; m = nm;
        float w_lane = (lane < cn) ? expf(att - m) : 0.f;
        float zs = w_lane;
#pragma unroll
        for (int off = 1; off < 64; off <<= 1)
            zs += __shfl_xor(zs, off, 64);
        Z += zs;
        for (int j = 0; j < cn; ++j) {
            float wj = __shfl(w_lane, j, 64);
            int pkj  = __shfl(pk, j, 64);
            int tj = pkj >> 4, rj = pkj & 15;
            acc += wj * cat[(size_t)tj * DIM + lane] * weight[rj * DIM + lane];
        }
    }
    catagg[(size_t)h * DIM + lane] = (s1 > s0) ? acc / Z : 0.f;
}

// K6: per-user aggregation + fused softmax gating — swizzled to matching XCD
__global__ void user_agg_kernel(const long long* __restrict__ nsorted2,
                                const int* __restrict__ uoff,
                                const float* __restrict__ cat,
                                const float* __restrict__ uemb,
                                const float* __restrict__ weight,
                                float* __restrict__ useragg) {
    int g = blockIdx.x & 7, lb = blockIdx.x >> 3;
    int wid = threadIdx.x >> 6, lane = threadIdx.x & 63;
    int lu = lb * 4 + wid;
    if (lu >= UR) return;
    int u = g * UR + lu;
    int s0 = uoff[u], s1 = uoff[u + 1];
    float acc = 0.f;
    for (int base = s0; base < s1; base += 64) {
        int cn = min(64, s1 - base);
        int c = 0; float v = 0.f;
        if (lane < cn) {
            unsigned long long pay = (unsigned long long)NTL(&nsorted2[base + lane]);
            c = (int)(unsigned int)(pay & 0xffffffffu);
            v = __uint_as_float((unsigned int)(pay >> 32));
        }
        for (int j = 0; j < cn; ++j) {
            int   cj = __shfl(c, j, 64);
            float vj = __shfl(v, j, 64);
            acc += vj * cat[(size_t)cj * DIM + lane];
        }
    }
    // gating: g = (softmax(u@W^T) @ W)[lane]
    float uv = uemb[(size_t)u * DIM + lane];
    float wl[N_RELM1], s[N_RELM1];
#pragma unroll
    for (int r = 0; r < N_RELM1; ++r) wl[r] = weight[r * DIM + lane];
#pragma unroll
    for (int r = 0; r < N_RELM1; ++r) {
        float p = uv * wl[r];
#pragma unroll
        for (int off = 1; off < 64; off <<= 1)
            p += __shfl_xor(p, off, 64);
        s[r] = p;
    }
    float mx = s[0];
#pragma unroll
    for (int r = 1; r < N_RELM1; ++r) mx = fmaxf(mx, s[r]);
    float Z = 0.f;
#pragma unroll
    for (int r = 0; r < N_RELM1; ++r) { s[r] = expf(s[r] - mx); Z += s[r]; }
    float gt = 0.f;
#pragma unroll
    for (int r = 0; r < N_RELM1; ++r) gt += s[r] * wl[r];
    gt /= Z;
    useragg[(size_t)u * DIM + lane] = acc * (1.f + gt);
}

extern "C" void kernel_launch(void* const* d_in, const int* in_sizes, int n_in,
                              void* d_out, int out_size, void* d_ws, size_t ws_size,
                              hipStream_t stream) {
    const float* cat    = (const float*)d_in[0];
    const float* uemb   = (const float*)d_in[1];
    const int*   eidx   = (const int*)d_in[2];
    const int*   etype  = (const int*)d_in[3];
    const int*   iidx   = (const int*)d_in[4];
    const float* ival   = (const float*)d_in[5];
    const float* weight = (const float*)d_in[6];

    float* catagg  = (float*)d_out;
    float* useragg = (float*)d_out + (size_t)N_CAT * DIM;

    // workspace layout (4-byte words)
    int* ws = (int*)d_ws;
    float* normsq   = (float*)ws;             // 1,500,000
    int*   hoff     = ws + 1500000;           // 100,001
    int*   uoff     = ws + 1600001;           // 50,001
    int*   hcnt     = ws + 1650002;           // 100,000 (counts, then cursors)
    int*   ucnt     = ws + 1750002;           // 50,000
    int*   hbtot    = ws + 1800002;           // 128
    int*   ubtot    = ws + 1800130;           // 128
    int*   esorted  = ws + 1800258;           // 1,500,000
    long long* nsorted2 = (long long*)(ws + 3300258); // 1,500,000 x 8B (8B-aligned offset)

    const int* head = eidx;
    const int* tail = eidx + E_EDGES;
    const int* iu   = iidx;
    const int* ic   = iidx + NNZ_E;

    hipMemsetAsync(hcnt, 0, (size_t)150000 * sizeof(int), stream); // hcnt+ucnt contiguous

    normsq_kernel<<<(N_CAT * 64 + 255) / 256, 256, 0, stream>>>(cat, weight, normsq);
    hist_kernel<<<2048, 256, 0, stream>>>(head, iu, hcnt, ucnt);
    scanA_kernel<<<98 + 49, 1024, 0, stream>>>(hcnt, hoff, ucnt, uoff, hbtot, ubtot);
    scanB_kernel<<<2, 128, 0, stream>>>(hbtot, ubtot);
    scanC_kernel<<<147, 1024, 0, stream>>>(hoff, uoff, hbtot, ubtot, hcnt, ucnt);
    scatter_kernel<<<2048, 256, 0, stream>>>(head, tail, etype, iu, ic, ival,
                                             hcnt, ucnt, esorted, nsorted2);
    cat_agg_kernel<<<25000, 256, 0, stream>>>(esorted, hoff, normsq, cat, weight, catagg);
    user_agg_kernel<<<8 * 1563, 256, 0, stream>>>(nsorted2, uoff, cat, uemb, weight, useragg);
}

// Round 6
// 481.149 us; speedup vs baseline: 1.2215x; 1.2215x over previous
//
#include <hip/hip_runtime.h>

#define N_CAT   100000
#define N_USERS 50000
#define DIM     64
#define N_RELM1 15
#define E_EDGES 1500000
#define NNZ_E   1500000

#define HPB   125           // heads per bucket
#define NB_H  800           // N_CAT / HPB
#define UPB   80            // users per bucket
#define NB_U  625           // N_USERS / UPB
#define NB_T  (NB_H + NB_U) // 1425
#define CAP_H 4096          // max edges per cat bucket (mean 1875)
#define CAP_U 4096          // max nnz per user bucket (mean 2400)

#define NTL(p) __builtin_nontemporal_load(p)

// K1: normsq[n][r] = sum_d (cat[n][d] * w[r][d])^2  — one wave per node
__global__ void normsq_kernel(const float* __restrict__ cat,
                              const float* __restrict__ weight,
                              float* __restrict__ normsq) {
    int gtid = blockIdx.x * blockDim.x + threadIdx.x;
    int node = gtid >> 6;
    int lane = threadIdx.x & 63;
    if (node >= N_CAT) return;
    float c = cat[node * DIM + lane];
    float myval = 0.f;
#pragma unroll
    for (int r = 0; r < N_RELM1; ++r) {
        float t = c * weight[r * DIM + lane];
        float s = t * t;
#pragma unroll
        for (int off = 1; off < 64; off <<= 1)
            s += __shfl_xor(s, off, 64);
        if (lane == r) myval = s;
    }
    if (lane < N_RELM1) normsq[node * N_RELM1 + lane] = myval;
}

// K2: bucket histogram (LDS-merged, single pass over edges)
__global__ void bhist_kernel(const int* __restrict__ head, const int* __restrict__ iu,
                             int* __restrict__ gcnt) {
    __shared__ int cnt[NB_T];
    for (int i = threadIdx.x; i < NB_T; i += blockDim.x) cnt[i] = 0;
    __syncthreads();
    int stride = gridDim.x * blockDim.x;
    for (int e = blockIdx.x * blockDim.x + threadIdx.x; e < E_EDGES; e += stride) {
        atomicAdd(&cnt[NTL(&head[e]) / HPB], 1);
        atomicAdd(&cnt[NB_H + NTL(&iu[e]) / UPB], 1);
    }
    __syncthreads();
    for (int i = threadIdx.x; i < NB_T; i += blockDim.x)
        if (cnt[i]) atomicAdd(&gcnt[i], cnt[i]);
}

// K3: single-block scan of 1425 bucket counts -> bases + cursor init
__global__ void bscan_kernel(const int* __restrict__ gcnt,
                             int* __restrict__ hbase, int* __restrict__ ubase,
                             int* __restrict__ cur) {
    __shared__ int s0[2048], s1[2048];
    int tid = threadIdx.x;
    for (int i = tid; i < 2048; i += 1024) s0[i] = (i < NB_T) ? gcnt[i] : 0;
    __syncthreads();
    int* a = s0; int* b = s1;
    for (int d = 1; d < 2048; d <<= 1) {
        for (int i = tid; i < 2048; i += 1024)
            b[i] = (i >= d) ? a[i] + a[i - d] : a[i];
        __syncthreads();
        int* t = a; a = b; b = t;
    }
    for (int i = tid; i < NB_T; i += 1024) {
        int excl = (i == 0) ? 0 : a[i - 1];
        if (i < NB_H) { hbase[i] = excl; cur[i] = excl; }
        else { int v = excl - E_EDGES; ubase[i - NB_H] = v; cur[i] = v; }
    }
    if (tid == 0) { hbase[NB_H] = E_EDGES; ubase[NB_U] = NNZ_E; }
}

// K4: one-pass binning — LDS count -> one global atomic per (block,bucket)
// to reserve a contiguous segment -> direct-indexed (mostly-contiguous) writes
__global__ void __launch_bounds__(1024)
binning_kernel(const int* __restrict__ head, const int* __restrict__ tail,
               const int* __restrict__ etype,
               const int* __restrict__ iu, const int* __restrict__ ic,
               const float* __restrict__ ival,
               int* __restrict__ cur,
               int* __restrict__ ebinned, unsigned long long* __restrict__ nbinned) {
    __shared__ int cnt[NB_T];
    __shared__ int base[NB_T];
    int CH = (E_EDGES + gridDim.x - 1) / gridDim.x;
    int c0 = blockIdx.x * CH;
    int c1 = min(c0 + CH, E_EDGES);
    for (int i = threadIdx.x; i < NB_T; i += 1024) cnt[i] = 0;
    __syncthreads();
    for (int e = c0 + threadIdx.x; e < c1; e += 1024) {
        atomicAdd(&cnt[NTL(&head[e]) / HPB], 1);
        atomicAdd(&cnt[NB_H + NTL(&iu[e]) / UPB], 1);
    }
    __syncthreads();
    for (int i = threadIdx.x; i < NB_T; i += 1024) {
        int c = cnt[i];
        if (c) base[i] = atomicAdd(&cur[i], c);
        cnt[i] = 0;
    }
    __syncthreads();
    for (int e = c0 + threadIdx.x; e < c1; e += 1024) {
        int h = NTL(&head[e]);
        int b = h / HPB;
        int r = atomicAdd(&cnt[b], 1);
        int pk = ((h - b * HPB) << 21) | (NTL(&tail[e]) << 4) | (NTL(&etype[e]) - 1);
        ebinned[base[b] + r] = pk;
        int u = NTL(&iu[e]);
        int b2 = NB_H + u / UPB;
        int r2 = atomicAdd(&cnt[b2], 1);
        unsigned long long w0 = (unsigned int)(((u - (b2 - NB_H) * UPB) << 17) | NTL(&ic[e]));
        unsigned long long w1 = (unsigned int)__float_as_uint(NTL(&ival[e]));
        nbinned[base[b2] + r2] = (w1 << 32) | w0;
    }
}

// K5: per-bucket LDS counting sort + online-softmax aggregation (8 waves/block)
__global__ void __launch_bounds__(512)
cat_bucket_agg(const int* __restrict__ ebinned, const int* __restrict__ hbase,
               const float* __restrict__ normsq, const float* __restrict__ cat,
               const float* __restrict__ weight, float* __restrict__ catagg) {
    __shared__ int sorted[CAP_H];
    __shared__ int cnt[HPB];
    __shared__ int ofs[HPB + 1];
    int b = blockIdx.x;
    int s0 = hbase[b], n = hbase[b + 1] - s0;
    for (int i = threadIdx.x; i < HPB; i += 512) cnt[i] = 0;
    __syncthreads();
    for (int i = threadIdx.x; i < n; i += 512)
        atomicAdd(&cnt[ebinned[s0 + i] >> 21], 1);
    __syncthreads();
    if (threadIdx.x == 0) {
        int acc = 0;
        for (int i = 0; i < HPB; ++i) { ofs[i] = acc; acc += cnt[i]; }
        ofs[HPB] = acc;
    }
    __syncthreads();
    for (int i = threadIdx.x; i < HPB; i += 512) cnt[i] = 0;
    __syncthreads();
    for (int i = threadIdx.x; i < n; i += 512) {
        int pk = ebinned[s0 + i];
        int hl = pk >> 21;
        int r = atomicAdd(&cnt[hl], 1);
        sorted[ofs[hl] + r] = pk;
    }
    __syncthreads();
    int wid = threadIdx.x >> 6, lane = threadIdx.x & 63;
    for (int hl = wid; hl < HPB; hl += 8) {
        int h = b * HPB + hl;
        int e0 = ofs[hl], e1 = ofs[hl + 1];
        float acc = 0.f, Z = 0.f, m = -1e30f;
        for (int tb = e0; tb < e1; tb += 64) {
            int cn = min(64, e1 - tb);
            float att = -1e30f;
            int pk = 0;
            if (lane < cn) {
                pk = sorted[tb + lane];
                int t = (pk >> 4) & 0x1FFFF, r = pk & 15;
                att = normsq[h * N_RELM1 + r] * normsq[(size_t)t * N_RELM1 + r];
            }
            float cm = att;
#pragma unroll
            for (int off = 1; off < 64; off <<= 1)
                cm = fmaxf(cm, __shfl_xor(cm, off, 64));
            float nm = fmaxf(m, cm);
            float scale = expf(m - nm);
            acc *= scale; Z *= scale; m = nm;
            float w_lane = (lane < cn) ? expf(att - m) : 0.f;
            float zs = w_lane;
#pragma unroll
            for (int off = 1; off < 64; off <<= 1)
                zs += __shfl_xor(zs, off, 64);
            Z += zs;
            for (int j = 0; j < cn; ++j) {
                float wj = __shfl(w_lane, j, 64);
                int pkj  = __shfl(pk, j, 64);
                int tj = (pkj >> 4) & 0x1FFFF, rj = pkj & 15;
                acc += wj * cat[(size_t)tj * DIM + lane] * weight[rj * DIM + lane];
            }
        }
        catagg[(size_t)h * DIM + lane] = (e1 > e0) ? acc / Z : 0.f;
    }
}

// K6: per-bucket LDS counting sort + user aggregation + fused gating
__global__ void __launch_bounds__(512)
user_bucket_agg(const unsigned long long* __restrict__ nbinned,
                const int* __restrict__ ubase,
                const float* __restrict__ cat,
                const float* __restrict__ uemb,
                const float* __restrict__ weight,
                float* __restrict__ useragg) {
    __shared__ unsigned long long sorted[CAP_U];
    __shared__ int cnt[UPB];
    __shared__ int ofs[UPB + 1];
    int b = blockIdx.x;
    int s0 = ubase[b], n = ubase[b + 1] - s0;
    for (int i = threadIdx.x; i < UPB; i += 512) cnt[i] = 0;
    __syncthreads();
    for (int i = threadIdx.x; i < n; i += 512) {
        unsigned int w0 = (unsigned int)nbinned[s0 + i];
        atomicAdd(&cnt[w0 >> 17], 1);
    }
    __syncthreads();
    if (threadIdx.x == 0) {
        int acc = 0;
        for (int i = 0; i < UPB; ++i) { ofs[i] = acc; acc += cnt[i]; }
        ofs[UPB] = acc;
    }
    __syncthreads();
    for (int i = threadIdx.x; i < UPB; i += 512) cnt[i] = 0;
    __syncthreads();
    for (int i = threadIdx.x; i < n; i += 512) {
        unsigned long long pay = nbinned[s0 + i];
        int ul = ((unsigned int)pay) >> 17;
        int r = atomicAdd(&cnt[ul], 1);
        sorted[ofs[ul] + r] = pay;
    }
    __syncthreads();
    int wid = threadIdx.x >> 6, lane = threadIdx.x & 63;
    for (int ul = wid; ul < UPB; ul += 8) {
        int u = b * UPB + ul;
        int e0 = ofs[ul], e1 = ofs[ul + 1];
        float acc = 0.f;
        for (int tb = e0; tb < e1; tb += 64) {
            int cn = min(64, e1 - tb);
            int c = 0; float v = 0.f;
            if (lane < cn) {
                unsigned long long pay = sorted[tb + lane];
                c = (int)((unsigned int)pay & 0x1FFFFu);
                v = __uint_as_float((unsigned int)(pay >> 32));
            }
            for (int j = 0; j < cn; ++j) {
                int   cj = __shfl(c, j, 64);
                float vj = __shfl(v, j, 64);
                acc += vj * cat[(size_t)cj * DIM + lane];
            }
        }
        // gating: (softmax(u@W^T) @ W)[lane]
        float uv = uemb[(size_t)u * DIM + lane];
        float wl[N_RELM1], sv[N_RELM1];
#pragma unroll
        for (int r = 0; r < N_RELM1; ++r) wl[r] = weight[r * DIM + lane];
#pragma unroll
        for (int r = 0; r < N_RELM1; ++r) {
            float p = uv * wl[r];
#pragma unroll
            for (int off = 1; off < 64; off <<= 1)
                p += __shfl_xor(p, off, 64);
            sv[r] = p;
        }
        float mx = sv[0];
#pragma unroll
        for (int r = 1; r < N_RELM1; ++r) mx = fmaxf(mx, sv[r]);
        float Zg = 0.f;
#pragma unroll
        for (int r = 0; r < N_RELM1; ++r) { sv[r] = expf(sv[r] - mx); Zg += sv[r]; }
        float gt = 0.f;
#pragma unroll
        for (int r = 0; r < N_RELM1; ++r) gt += sv[r] * wl[r];
        gt /= Zg;
        useragg[(size_t)u * DIM + lane] = acc * (1.f + gt);
    }
}

extern "C" void kernel_launch(void* const* d_in, const int* in_sizes, int n_in,
                              void* d_out, int out_size, void* d_ws, size_t ws_size,
                              hipStream_t stream) {
    const float* cat    = (const float*)d_in[0];
    const float* uemb   = (const float*)d_in[1];
    const int*   eidx   = (const int*)d_in[2];
    const int*   etype  = (const int*)d_in[3];
    const int*   iidx   = (const int*)d_in[4];
    const float* ival   = (const float*)d_in[5];
    const float* weight = (const float*)d_in[6];

    float* catagg  = (float*)d_out;
    float* useragg = (float*)d_out + (size_t)N_CAT * DIM;

    // workspace layout (4-byte words)
    int* ws = (int*)d_ws;
    float* normsq   = (float*)ws;                              // 1,500,000
    int*   ebinned  = ws + 1500000;                            // 1,500,000
    unsigned long long* nbinned = (unsigned long long*)(ws + 3000000); // 1.5M x 8B (8B-aligned)
    int*   gcnt     = ws + 6000000;                            // 1425
    int*   hbase    = ws + 6001425;                            // 801
    int*   ubase    = ws + 6002226;                            // 626
    int*   cur      = ws + 6002852;                            // 1425

    const int* head = eidx;
    const int* tail = eidx + E_EDGES;
    const int* iu   = iidx;
    const int* ic   = iidx + NNZ_E;

    hipMemsetAsync(gcnt, 0, (size_t)NB_T * sizeof(int), stream);

    normsq_kernel<<<(N_CAT * 64 + 255) / 256, 256, 0, stream>>>(cat, weight, normsq);
    bhist_kernel<<<256, 256, 0, stream>>>(head, iu, gcnt);
    bscan_kernel<<<1, 1024, 0, stream>>>(gcnt, hbase, ubase, cur);
    binning_kernel<<<256, 1024, 0, stream>>>(head, tail, etype, iu, ic, ival,
                                             cur, ebinned, nbinned);
    cat_bucket_agg<<<NB_H, 512, 0, stream>>>(ebinned, hbase, normsq, cat, weight, catagg);
    user_bucket_agg<<<NB_U, 512, 0, stream>>>(nbinned, ubase, cat, uemb, weight, useragg);
}

// Round 7
// 387.826 us; speedup vs baseline: 1.5155x; 1.2406x over previous
//
#include <hip/hip_runtime.h>

#define N_CAT   100000
#define N_USERS 50000
#define DIM     64
#define N_RELM1 15
#define E_EDGES 1500000
#define NNZ_E   1500000

#define HPB   125           // heads per bucket
#define NB_H  800           // N_CAT / HPB
#define UPB   80            // users per bucket
#define NB_U  625           // N_USERS / UPB
#define NB_T  (NB_H + NB_U) // 1425
#define CAP_H 4096          // max edges per cat bucket (mean 1875)
#define CAP_U 4096          // max nnz per user bucket (mean 2400)

#define NTL(p) __builtin_nontemporal_load(p)

// K1: normsq[n][r] = sum_d (cat[n][d] * w[r][d])^2  — one wave per node
__global__ void normsq_kernel(const float* __restrict__ cat,
                              const float* __restrict__ weight,
                              float* __restrict__ normsq) {
    int gtid = blockIdx.x * blockDim.x + threadIdx.x;
    int node = gtid >> 6;
    int lane = threadIdx.x & 63;
    if (node >= N_CAT) return;
    float c = cat[node * DIM + lane];
    float myval = 0.f;
#pragma unroll
    for (int r = 0; r < N_RELM1; ++r) {
        float t = c * weight[r * DIM + lane];
        float s = t * t;
#pragma unroll
        for (int off = 1; off < 64; off <<= 1)
            s += __shfl_xor(s, off, 64);
        if (lane == r) myval = s;
    }
    if (lane < N_RELM1) normsq[node * N_RELM1 + lane] = myval;
}

// K2: bucket histogram (LDS-merged, single pass over edges)
__global__ void bhist_kernel(const int* __restrict__ head, const int* __restrict__ iu,
                             int* __restrict__ gcnt) {
    __shared__ int cnt[NB_T];
    for (int i = threadIdx.x; i < NB_T; i += blockDim.x) cnt[i] = 0;
    __syncthreads();
    int stride = gridDim.x * blockDim.x;
    for (int e = blockIdx.x * blockDim.x + threadIdx.x; e < E_EDGES; e += stride) {
        atomicAdd(&cnt[NTL(&head[e]) / HPB], 1);
        atomicAdd(&cnt[NB_H + NTL(&iu[e]) / UPB], 1);
    }
    __syncthreads();
    for (int i = threadIdx.x; i < NB_T; i += blockDim.x)
        if (cnt[i]) atomicAdd(&gcnt[i], cnt[i]);
}

// K3: single-block scan of 1425 bucket counts -> bases + cursor init
__global__ void bscan_kernel(const int* __restrict__ gcnt,
                             int* __restrict__ hbase, int* __restrict__ ubase,
                             int* __restrict__ cur) {
    __shared__ int s0[2048], s1[2048];
    int tid = threadIdx.x;
    for (int i = tid; i < 2048; i += 1024) s0[i] = (i < NB_T) ? gcnt[i] : 0;
    __syncthreads();
    int* a = s0; int* b = s1;
    for (int d = 1; d < 2048; d <<= 1) {
        for (int i = tid; i < 2048; i += 1024)
            b[i] = (i >= d) ? a[i] + a[i - d] : a[i];
        __syncthreads();
        int* t = a; a = b; b = t;
    }
    for (int i = tid; i < NB_T; i += 1024) {
        int excl = (i == 0) ? 0 : a[i - 1];
        if (i < NB_H) { hbase[i] = excl; cur[i] = excl; }
        else { int v = excl - E_EDGES; ubase[i - NB_H] = v; cur[i] = v; }
    }
    if (tid == 0) { hbase[NB_H] = E_EDGES; ubase[NB_U] = NNZ_E; }
}

// K4: one-pass binning — LDS count -> one global atomic per (block,bucket)
__global__ void __launch_bounds__(1024)
binning_kernel(const int* __restrict__ head, const int* __restrict__ tail,
               const int* __restrict__ etype,
               const int* __restrict__ iu, const int* __restrict__ ic,
               const float* __restrict__ ival,
               int* __restrict__ cur,
               int* __restrict__ ebinned, unsigned long long* __restrict__ nbinned) {
    __shared__ int cnt[NB_T];
    __shared__ int base[NB_T];
    int CH = (E_EDGES + gridDim.x - 1) / gridDim.x;
    int c0 = blockIdx.x * CH;
    int c1 = min(c0 + CH, E_EDGES);
    for (int i = threadIdx.x; i < NB_T; i += 1024) cnt[i] = 0;
    __syncthreads();
    for (int e = c0 + threadIdx.x; e < c1; e += 1024) {
        atomicAdd(&cnt[NTL(&head[e]) / HPB], 1);
        atomicAdd(&cnt[NB_H + NTL(&iu[e]) / UPB], 1);
    }
    __syncthreads();
    for (int i = threadIdx.x; i < NB_T; i += 1024) {
        int c = cnt[i];
        if (c) base[i] = atomicAdd(&cur[i], c);
        cnt[i] = 0;
    }
    __syncthreads();
    for (int e = c0 + threadIdx.x; e < c1; e += 1024) {
        int h = NTL(&head[e]);
        int b = h / HPB;
        int r = atomicAdd(&cnt[b], 1);
        int pk = ((h - b * HPB) << 21) | (NTL(&tail[e]) << 4) | (NTL(&etype[e]) - 1);
        ebinned[base[b] + r] = pk;
        int u = NTL(&iu[e]);
        int b2 = NB_H + u / UPB;
        int r2 = atomicAdd(&cnt[b2], 1);
        unsigned long long w0 = (unsigned int)(((u - (b2 - NB_H) * UPB) << 17) | NTL(&ic[e]));
        unsigned long long w1 = (unsigned int)__float_as_uint(NTL(&ival[e]));
        nbinned[base[b2] + r2] = (w1 << 32) | w0;
    }
}

// K5: per-bucket LDS counting sort + two-pass softmax + broadcast-gather agg
__global__ void __launch_bounds__(512)
cat_bucket_agg(const int* __restrict__ ebinned, const int* __restrict__ hbase,
               const float* __restrict__ normsq, const float* __restrict__ cat,
               const float* __restrict__ weight, float* __restrict__ catagg) {
    __shared__ int   sorted[CAP_H];
    __shared__ float wexp[CAP_H];
    __shared__ float wlds[N_RELM1 * DIM];
    __shared__ int cnt[HPB];
    __shared__ int ofs[HPB + 1];
    int b = blockIdx.x;
    int s0 = hbase[b], n = hbase[b + 1] - s0;
    for (int i = threadIdx.x; i < N_RELM1 * DIM; i += 512) wlds[i] = weight[i];
    for (int i = threadIdx.x; i < HPB; i += 512) cnt[i] = 0;
    __syncthreads();
    for (int i = threadIdx.x; i < n; i += 512)
        atomicAdd(&cnt[ebinned[s0 + i] >> 21], 1);
    __syncthreads();
    if (threadIdx.x == 0) {
        int acc = 0;
        for (int i = 0; i < HPB; ++i) { ofs[i] = acc; acc += cnt[i]; }
        ofs[HPB] = acc;
    }
    __syncthreads();
    for (int i = threadIdx.x; i < HPB; i += 512) cnt[i] = 0;
    __syncthreads();
    for (int i = threadIdx.x; i < n; i += 512) {
        int pk = ebinned[s0 + i];
        int hl = pk >> 21;
        int r = atomicAdd(&cnt[hl], 1);
        sorted[ofs[hl] + r] = pk;
    }
    __syncthreads();
    int wid = threadIdx.x >> 6, lane = threadIdx.x & 63;
    for (int hl = wid; hl < HPB; hl += 8) {
        int h = b * HPB + hl;
        int e0 = ofs[hl], e1 = ofs[hl + 1];
        // phase A: att per edge (lane-parallel), wave max, exp-weights to LDS, wave sum
        float m = -1e30f;
        for (int t = e0 + lane; t < e1; t += 64) {
            int pk = sorted[t];
            int tj = (pk >> 4) & 0x1FFFF, rj = pk & 15;
            float att = normsq[h * N_RELM1 + rj] * normsq[(size_t)tj * N_RELM1 + rj];
            wexp[t] = att;
            m = fmaxf(m, att);
        }
#pragma unroll
        for (int off = 1; off < 64; off <<= 1)
            m = fmaxf(m, __shfl_xor(m, off, 64));
        float Z = 0.f;
        for (int t = e0 + lane; t < e1; t += 64) {
            float w = expf(wexp[t] - m);
            wexp[t] = w;
            Z += w;
        }
#pragma unroll
        for (int off = 1; off < 64; off <<= 1)
            Z += __shfl_xor(Z, off, 64);
        // phase B: broadcast-gather, 4-wide MLP
        float acc = 0.f;
        for (int j = e0; j < e1; j += 4) {
#pragma unroll
            for (int k = 0; k < 4; ++k) {
                int idx = j + k;
                bool ok = idx < e1;
                idx = ok ? idx : e0;
                int pk = sorted[idx];
                float w = ok ? wexp[idx] : 0.f;
                int tj = (pk >> 4) & 0x1FFFF, rj = pk & 15;
                acc += w * cat[(size_t)tj * DIM + lane] * wlds[rj * DIM + lane];
            }
        }
        catagg[(size_t)h * DIM + lane] = (e1 > e0) ? acc / Z : 0.f;
    }
}

// K6: per-bucket LDS counting sort + broadcast-gather user agg + fused gating
__global__ void __launch_bounds__(512)
user_bucket_agg(const unsigned long long* __restrict__ nbinned,
                const int* __restrict__ ubase,
                const float* __restrict__ cat,
                const float* __restrict__ uemb,
                const float* __restrict__ weight,
                float* __restrict__ useragg) {
    __shared__ unsigned long long sorted[CAP_U];
    __shared__ int cnt[UPB];
    __shared__ int ofs[UPB + 1];
    int b = blockIdx.x;
    int s0 = ubase[b], n = ubase[b + 1] - s0;
    for (int i = threadIdx.x; i < UPB; i += 512) cnt[i] = 0;
    __syncthreads();
    for (int i = threadIdx.x; i < n; i += 512) {
        unsigned int w0 = (unsigned int)nbinned[s0 + i];
        atomicAdd(&cnt[w0 >> 17], 1);
    }
    __syncthreads();
    if (threadIdx.x == 0) {
        int acc = 0;
        for (int i = 0; i < UPB; ++i) { ofs[i] = acc; acc += cnt[i]; }
        ofs[UPB] = acc;
    }
    __syncthreads();
    for (int i = threadIdx.x; i < UPB; i += 512) cnt[i] = 0;
    __syncthreads();
    for (int i = threadIdx.x; i < n; i += 512) {
        unsigned long long pay = nbinned[s0 + i];
        int ul = ((unsigned int)pay) >> 17;
        int r = atomicAdd(&cnt[ul], 1);
        sorted[ofs[ul] + r] = pay;
    }
    __syncthreads();
    int wid = threadIdx.x >> 6, lane = threadIdx.x & 63;
    for (int ul = wid; ul < UPB; ul += 8) {
        int u = b * UPB + ul;
        int e0 = ofs[ul], e1 = ofs[ul + 1];
        float acc = 0.f;
        for (int j = e0; j < e1; j += 4) {
#pragma unroll
            for (int k = 0; k < 4; ++k) {
                int idx = j + k;
                bool ok = idx < e1;
                idx = ok ? idx : e0;
                unsigned long long pay = sorted[idx];
                float v = ok ? __uint_as_float((unsigned int)(pay >> 32)) : 0.f;
                int c = (int)((unsigned int)pay & 0x1FFFFu);
                acc += v * cat[(size_t)c * DIM + lane];
            }
        }
        // gating: (softmax(u@W^T) @ W)[lane]
        float uv = uemb[(size_t)u * DIM + lane];
        float wl[N_RELM1], sv[N_RELM1];
#pragma unroll
        for (int r = 0; r < N_RELM1; ++r) wl[r] = weight[r * DIM + lane];
#pragma unroll
        for (int r = 0; r < N_RELM1; ++r) {
            float p = uv * wl[r];
#pragma unroll
            for (int off = 1; off < 64; off <<= 1)
                p += __shfl_xor(p, off, 64);
            sv[r] = p;
        }
        float mx = sv[0];
#pragma unroll
        for (int r = 1; r < N_RELM1; ++r) mx = fmaxf(mx, sv[r]);
        float Zg = 0.f;
#pragma unroll
        for (int r = 0; r < N_RELM1; ++r) { sv[r] = expf(sv[r] - mx); Zg += sv[r]; }
        float gt = 0.f;
#pragma unroll
        for (int r = 0; r < N_RELM1; ++r) gt += sv[r] * wl[r];
        gt /= Zg;
        useragg[(size_t)u * DIM + lane] = acc * (1.f + gt);
    }
}

extern "C" void kernel_launch(void* const* d_in, const int* in_sizes, int n_in,
                              void* d_out, int out_size, void* d_ws, size_t ws_size,
                              hipStream_t stream) {
    const float* cat    = (const float*)d_in[0];
    const float* uemb   = (const float*)d_in[1];
    const int*   eidx   = (const int*)d_in[2];
    const int*   etype  = (const int*)d_in[3];
    const int*   iidx   = (const int*)d_in[4];
    const float* ival   = (const float*)d_in[5];
    const float* weight = (const float*)d_in[6];

    float* catagg  = (float*)d_out;
    float* useragg = (float*)d_out + (size_t)N_CAT * DIM;

    // workspace layout (4-byte words)
    int* ws = (int*)d_ws;
    float* normsq   = (float*)ws;                              // 1,500,000
    int*   ebinned  = ws + 1500000;                            // 1,500,000
    unsigned long long* nbinned = (unsigned long long*)(ws + 3000000); // 1.5M x 8B
    int*   gcnt     = ws + 6000000;                            // 1425
    int*   hbase    = ws + 6001425;                            // 801
    int*   ubase    = ws + 6002226;                            // 626
    int*   cur      = ws + 6002852;                            // 1425

    const int* head = eidx;
    const int* tail = eidx + E_EDGES;
    const int* iu   = iidx;
    const int* ic   = iidx + NNZ_E;

    hipMemsetAsync(gcnt, 0, (size_t)NB_T * sizeof(int), stream);

    normsq_kernel<<<(N_CAT * 64 + 255) / 256, 256, 0, stream>>>(cat, weight, normsq);
    bhist_kernel<<<256, 256, 0, stream>>>(head, iu, gcnt);
    bscan_kernel<<<1, 1024, 0, stream>>>(gcnt, hbase, ubase, cur);
    binning_kernel<<<256, 1024, 0, stream>>>(head, tail, etype, iu, ic, ival,
                                             cur, ebinned, nbinned);
    cat_bucket_agg<<<NB_H, 512, 0, stream>>>(ebinned, hbase, normsq, cat, weight, catagg);
    user_bucket_agg<<<NB_U, 512, 0, stream>>>(nbinned, ubase, cat, uemb, weight, useragg);
}

// Round 8
// 300.216 us; speedup vs baseline: 1.9577x; 1.2918x over previous
//
#include <hip/hip_runtime.h>

#define N_CAT   100000
#define N_USERS 50000
#define DIM     64
#define N_RELM1 15
#define E_EDGES 1500000
#define NNZ_E   1500000

#define HPB   125           // heads per bucket
#define NB_H  800           // N_CAT / HPB
#define UPB   80            // users per bucket
#define NB_U  625           // N_USERS / UPB
#define NB_T  (NB_H + NB_U) // 1425
#define CAP_H 4096
#define CAP_U 4096

#define NS_TILES 1563       // ceil(N_CAT/64)
#define GT_TILES 782        // ceil(N_USERS/64)

#define NTL(p) __builtin_nontemporal_load(p)

__device__ __forceinline__ unsigned short f2bf(float v) {
    unsigned int ub = __float_as_uint(v);
    return (unsigned short)((ub + 0x7FFF + ((ub >> 16) & 1)) >> 16);
}
__device__ __forceinline__ float bf2f(unsigned short s) {
    return __uint_as_float(((unsigned int)s) << 16);
}

// K1: prep — tile-matmul normsq (no cross-lane), bf16 cat table, gating factors.
// blocks [0, NS_TILES): normsq + cat16 for 64 nodes
// blocks [NS_TILES, NS_TILES+GT_TILES): gfac -> useragg region of d_out
template <bool USE16>
__global__ void __launch_bounds__(256)
prep_kernel(const float* __restrict__ cat, const float* __restrict__ uemb,
            const float* __restrict__ weight,
            float* __restrict__ normsq, unsigned short* __restrict__ cat16,
            float* __restrict__ gfac) {
    int t = threadIdx.x;
    int lane = t & 63, wid = t >> 6;
    if (blockIdx.x < NS_TILES) {
        __shared__ float c2[64 * 65];
        __shared__ float w2t[64 * 16];   // [d][r] of w^2
        __shared__ float nsqT[16 * 64];  // [r][n]
        int nbase = blockIdx.x * 64;
        int nclamp = min(64, N_CAT - nbase);
        for (int i = t; i < 1024; i += 256) {
            int d = i >> 4, r = i & 15;
            float w = (r < N_RELM1) ? weight[r * 64 + d] : 0.f;
            w2t[i] = w * w;
        }
        for (int i = t; i < 4096; i += 256) {
            int row = i >> 6, d = i & 63;
            float v = (row < nclamp) ? cat[(size_t)(nbase + row) * 64 + d] : 0.f;
            c2[row * 65 + d] = v * v;
            if (USE16 && row < nclamp)
                cat16[(size_t)(nbase + row) * 64 + d] = f2bf(v);
        }
        __syncthreads();
        float a0 = 0, a1 = 0, a2 = 0, a3 = 0;
        int r0 = wid * 4;
#pragma unroll 8
        for (int d = 0; d < 64; ++d) {
            float c = c2[lane * 65 + d];
            float4 w4 = *(float4*)&w2t[d * 16 + r0];
            a0 += c * w4.x; a1 += c * w4.y; a2 += c * w4.z; a3 += c * w4.w;
        }
        nsqT[(r0 + 0) * 64 + lane] = a0;
        nsqT[(r0 + 1) * 64 + lane] = a1;
        nsqT[(r0 + 2) * 64 + lane] = a2;
        nsqT[(r0 + 3) * 64 + lane] = a3;
        __syncthreads();
        for (int i = t; i < nclamp * 15; i += 256) {
            int n = i / 15, r = i - n * 15;
            normsq[(size_t)(nbase + n) * 15 + r] = nsqT[r * 64 + n];
        }
    } else {
        __shared__ float ut[64 * 65];
        __shared__ float wt[64 * 16];   // [d][r]
        __shared__ float wrT[16 * 64];  // [r][d]
        __shared__ float st[64 * 16];   // scores [u][r]
        __shared__ float pt[64 * 16];   // probs  [u][r]
        int ub_ = (blockIdx.x - NS_TILES) * 64;
        int uclamp = min(64, N_USERS - ub_);
        for (int i = t; i < 1024; i += 256) {
            int d = i >> 4, r = i & 15;
            float w = (r < N_RELM1) ? weight[r * 64 + d] : 0.f;
            wt[i] = w;
            wrT[r * 64 + d] = w;
        }
        for (int i = t; i < 4096; i += 256) {
            int row = i >> 6, d = i & 63;
            ut[row * 65 + d] = (row < uclamp) ? uemb[(size_t)(ub_ + row) * 64 + d] : 0.f;
        }
        __syncthreads();
        float a0 = 0, a1 = 0, a2 = 0, a3 = 0;
        int r0 = wid * 4;
#pragma unroll 8
        for (int d = 0; d < 64; ++d) {
            float c = ut[lane * 65 + d];
            float4 w4 = *(float4*)&wt[d * 16 + r0];
            a0 += c * w4.x; a1 += c * w4.y; a2 += c * w4.z; a3 += c * w4.w;
        }
        st[lane * 16 + r0 + 0] = a0;
        st[lane * 16 + r0 + 1] = a1;
        st[lane * 16 + r0 + 2] = a2;
        st[lane * 16 + r0 + 3] = a3;
        __syncthreads();
        if (wid == 0) {
            float mx = -1e30f;
            float pv[N_RELM1];
#pragma unroll
            for (int r = 0; r < N_RELM1; ++r) mx = fmaxf(mx, st[lane * 16 + r]);
            float Z = 0.f;
#pragma unroll
            for (int r = 0; r < N_RELM1; ++r) { pv[r] = expf(st[lane * 16 + r] - mx); Z += pv[r]; }
            float inv = 1.f / Z;
#pragma unroll
            for (int r = 0; r < N_RELM1; ++r) pt[lane * 16 + r] = pv[r] * inv;
        }
        __syncthreads();
        for (int i = t; i < uclamp * 64; i += 256) {
            int u = i >> 6, d = i & 63;
            float g = 0.f;
#pragma unroll
            for (int r = 0; r < N_RELM1; ++r) g += pt[u * 16 + r] * wrT[r * 64 + d];
            gfac[(size_t)(ub_ + u) * 64 + d] = g;
        }
    }
}

// K2: bucket histogram
__global__ void bhist_kernel(const int* __restrict__ head, const int* __restrict__ iu,
                             int* __restrict__ gcnt) {
    __shared__ int cnt[NB_T];
    for (int i = threadIdx.x; i < NB_T; i += blockDim.x) cnt[i] = 0;
    __syncthreads();
    int stride = gridDim.x * blockDim.x;
    for (int e = blockIdx.x * blockDim.x + threadIdx.x; e < E_EDGES; e += stride) {
        atomicAdd(&cnt[NTL(&head[e]) / HPB], 1);
        atomicAdd(&cnt[NB_H + NTL(&iu[e]) / UPB], 1);
    }
    __syncthreads();
    for (int i = threadIdx.x; i < NB_T; i += blockDim.x)
        if (cnt[i]) atomicAdd(&gcnt[i], cnt[i]);
}

// K3: single-block scan of bucket counts
__global__ void bscan_kernel(const int* __restrict__ gcnt,
                             int* __restrict__ hbase, int* __restrict__ ubase,
                             int* __restrict__ cur) {
    __shared__ int s0[2048], s1[2048];
    int tid = threadIdx.x;
    for (int i = tid; i < 2048; i += 1024) s0[i] = (i < NB_T) ? gcnt[i] : 0;
    __syncthreads();
    int* a = s0; int* b = s1;
    for (int d = 1; d < 2048; d <<= 1) {
        for (int i = tid; i < 2048; i += 1024)
            b[i] = (i >= d) ? a[i] + a[i - d] : a[i];
        __syncthreads();
        int* t = a; a = b; b = t;
    }
    for (int i = tid; i < NB_T; i += 1024) {
        int excl = (i == 0) ? 0 : a[i - 1];
        if (i < NB_H) { hbase[i] = excl; cur[i] = excl; }
        else { int v = excl - E_EDGES; ubase[i - NB_H] = v; cur[i] = v; }
    }
    if (tid == 0) { hbase[NB_H] = E_EDGES; ubase[NB_U] = NNZ_E; }
}

// K4: one-pass binning
__global__ void __launch_bounds__(1024)
binning_kernel(const int* __restrict__ head, const int* __restrict__ tail,
               const int* __restrict__ etype,
               const int* __restrict__ iu, const int* __restrict__ ic,
               const float* __restrict__ ival,
               int* __restrict__ cur,
               int* __restrict__ ebinned, unsigned long long* __restrict__ nbinned) {
    __shared__ int cnt[NB_T];
    __shared__ int base[NB_T];
    int CH = (E_EDGES + gridDim.x - 1) / gridDim.x;
    int c0 = blockIdx.x * CH;
    int c1 = min(c0 + CH, E_EDGES);
    for (int i = threadIdx.x; i < NB_T; i += 1024) cnt[i] = 0;
    __syncthreads();
    for (int e = c0 + threadIdx.x; e < c1; e += 1024) {
        atomicAdd(&cnt[NTL(&head[e]) / HPB], 1);
        atomicAdd(&cnt[NB_H + NTL(&iu[e]) / UPB], 1);
    }
    __syncthreads();
    for (int i = threadIdx.x; i < NB_T; i += 1024) {
        int c = cnt[i];
        if (c) base[i] = atomicAdd(&cur[i], c);
        cnt[i] = 0;
    }
    __syncthreads();
    for (int e = c0 + threadIdx.x; e < c1; e += 1024) {
        int h = NTL(&head[e]);
        int b = h / HPB;
        int r = atomicAdd(&cnt[b], 1);
        int pk = ((h - b * HPB) << 21) | (NTL(&tail[e]) << 4) | (NTL(&etype[e]) - 1);
        ebinned[base[b] + r] = pk;
        int u = NTL(&iu[e]);
        int b2 = NB_H + u / UPB;
        int r2 = atomicAdd(&cnt[b2], 1);
        unsigned long long w0 = (unsigned int)(((u - (b2 - NB_H) * UPB) << 17) | NTL(&ic[e]));
        unsigned long long w1 = (unsigned int)__float_as_uint(NTL(&ival[e]));
        nbinned[base[b2] + r2] = (w1 << 32) | w0;
    }
}

// K5: per-bucket LDS counting sort + two-pass softmax + broadcast-gather agg
template <bool USE16>
__global__ void __launch_bounds__(512)
cat_bucket_agg(const int* __restrict__ ebinned, const int* __restrict__ hbase,
               const float* __restrict__ normsq, const float* __restrict__ catf,
               const unsigned short* __restrict__ cat16,
               const float* __restrict__ weight, float* __restrict__ catagg) {
    __shared__ int   sorted[CAP_H];
    __shared__ float wexp[CAP_H];
    __shared__ float wlds[N_RELM1 * DIM];
    __shared__ int cnt[HPB];
    __shared__ int ofs[HPB + 1];
    int b = blockIdx.x;
    int s0 = hbase[b], n = hbase[b + 1] - s0;
    for (int i = threadIdx.x; i < N_RELM1 * DIM; i += 512) wlds[i] = weight[i];
    for (int i = threadIdx.x; i < HPB; i += 512) cnt[i] = 0;
    __syncthreads();
    for (int i = threadIdx.x; i < n; i += 512)
        atomicAdd(&cnt[ebinned[s0 + i] >> 21], 1);
    __syncthreads();
    if (threadIdx.x == 0) {
        int acc = 0;
        for (int i = 0; i < HPB; ++i) { ofs[i] = acc; acc += cnt[i]; }
        ofs[HPB] = acc;
    }
    __syncthreads();
    for (int i = threadIdx.x; i < HPB; i += 512) cnt[i] = 0;
    __syncthreads();
    for (int i = threadIdx.x; i < n; i += 512) {
        int pk = ebinned[s0 + i];
        int hl = pk >> 21;
        int r = atomicAdd(&cnt[hl], 1);
        sorted[ofs[hl] + r] = pk;
    }
    __syncthreads();
    int wid = threadIdx.x >> 6, lane = threadIdx.x & 63;
    for (int hl = wid; hl < HPB; hl += 8) {
        int h = b * HPB + hl;
        int e0 = ofs[hl], e1 = ofs[hl + 1];
        float m = -1e30f;
        for (int t = e0 + lane; t < e1; t += 64) {
            int pk = sorted[t];
            int tj = (pk >> 4) & 0x1FFFF, rj = pk & 15;
            float att = normsq[h * N_RELM1 + rj] * normsq[(size_t)tj * N_RELM1 + rj];
            wexp[t] = att;
            m = fmaxf(m, att);
        }
#pragma unroll
        for (int off = 1; off < 64; off <<= 1)
            m = fmaxf(m, __shfl_xor(m, off, 64));
        float Z = 0.f;
        for (int t = e0 + lane; t < e1; t += 64) {
            float w = expf(wexp[t] - m);
            wexp[t] = w;
            Z += w;
        }
#pragma unroll
        for (int off = 1; off < 64; off <<= 1)
            Z += __shfl_xor(Z, off, 64);
        float acc = 0.f;
        for (int j = e0; j < e1; j += 4) {
#pragma unroll
            for (int k = 0; k < 4; ++k) {
                int idx = j + k;
                bool ok = idx < e1;
                idx = ok ? idx : e0;
                int pk = sorted[idx];
                float w = ok ? wexp[idx] : 0.f;
                int tj = (pk >> 4) & 0x1FFFF, rj = pk & 15;
                float cv = USE16 ? bf2f(cat16[(size_t)tj * DIM + lane])
                                 : catf[(size_t)tj * DIM + lane];
                acc += w * cv * wlds[rj * DIM + lane];
            }
        }
        catagg[(size_t)h * DIM + lane] = (e1 > e0) ? acc / Z : 0.f;
    }
}

// K6: per-bucket LDS counting sort + broadcast-gather user agg; gating read from gfac
template <bool USE16>
__global__ void __launch_bounds__(512)
user_bucket_agg(const unsigned long long* __restrict__ nbinned,
                const int* __restrict__ ubase,
                const float* __restrict__ catf,
                const unsigned short* __restrict__ cat16,
                float* __restrict__ useragg) {
    __shared__ unsigned long long sorted[CAP_U];
    __shared__ int cnt[UPB];
    __shared__ int ofs[UPB + 1];
    int b = blockIdx.x;
    int s0 = ubase[b], n = ubase[b + 1] - s0;
    for (int i = threadIdx.x; i < UPB; i += 512) cnt[i] = 0;
    __syncthreads();
    for (int i = threadIdx.x; i < n; i += 512) {
        unsigned int w0 = (unsigned int)nbinned[s0 + i];
        atomicAdd(&cnt[w0 >> 17], 1);
    }
    __syncthreads();
    if (threadIdx.x == 0) {
        int acc = 0;
        for (int i = 0; i < UPB; ++i) { ofs[i] = acc; acc += cnt[i]; }
        ofs[UPB] = acc;
    }
    __syncthreads();
    for (int i = threadIdx.x; i < UPB; i += 512) cnt[i] = 0;
    __syncthreads();
    for (int i = threadIdx.x; i < n; i += 512) {
        unsigned long long pay = nbinned[s0 + i];
        int ul = ((unsigned int)pay) >> 17;
        int r = atomicAdd(&cnt[ul], 1);
        sorted[ofs[ul] + r] = pay;
    }
    __syncthreads();
    int wid = threadIdx.x >> 6, lane = threadIdx.x & 63;
    for (int ul = wid; ul < UPB; ul += 8) {
        int u = b * UPB + ul;
        int e0 = ofs[ul], e1 = ofs[ul + 1];
        float gf = useragg[(size_t)u * DIM + lane];  // precomputed gating factor
        float acc = 0.f;
        for (int j = e0; j < e1; j += 8) {
#pragma unroll
            for (int k = 0; k < 8; ++k) {
                int idx = j + k;
                bool ok = idx < e1;
                idx = ok ? idx : e0;
                unsigned long long pay = sorted[idx];
                float v = ok ? __uint_as_float((unsigned int)(pay >> 32)) : 0.f;
                int c = (int)((unsigned int)pay & 0x1FFFFu);
                float cv = USE16 ? bf2f(cat16[(size_t)c * DIM + lane])
                                 : catf[(size_t)c * DIM + lane];
                acc += v * cv;
            }
        }
        useragg[(size_t)u * DIM + lane] = acc * (1.f + gf);
    }
}

extern "C" void kernel_launch(void* const* d_in, const int* in_sizes, int n_in,
                              void* d_out, int out_size, void* d_ws, size_t ws_size,
                              hipStream_t stream) {
    const float* cat    = (const float*)d_in[0];
    const float* uemb   = (const float*)d_in[1];
    const int*   eidx   = (const int*)d_in[2];
    const int*   etype  = (const int*)d_in[3];
    const int*   iidx   = (const int*)d_in[4];
    const float* ival   = (const float*)d_in[5];
    const float* weight = (const float*)d_in[6];

    float* catagg  = (float*)d_out;
    float* useragg = (float*)d_out + (size_t)N_CAT * DIM;

    // workspace layout (4-byte words)
    int* ws = (int*)d_ws;
    float* normsq   = (float*)ws;                              // [0, 1.5M)
    int*   ebinned  = ws + 1500000;                            // [1.5M, 3M)
    unsigned long long* nbinned = (unsigned long long*)(ws + 3000000); // [3M, 6M)
    int*   gcnt     = ws + 6000000;                            // 1425
    int*   hbase    = ws + 6001425;                            // 801
    int*   ubase    = ws + 6002226;                            // 626
    int*   cur      = ws + 6002852;                            // 1425
    unsigned short* cat16 = (unsigned short*)(ws + 6004278);   // 6.4M ushorts (3.2M words)
    const size_t NEED16 = (size_t)(6004278 + 3200000) * 4;
    bool use16 = ws_size >= NEED16;

    const int* head = eidx;
    const int* tail = eidx + E_EDGES;
    const int* iu   = iidx;
    const int* ic   = iidx + NNZ_E;

    hipMemsetAsync(gcnt, 0, (size_t)NB_T * sizeof(int), stream);

    if (use16) {
        prep_kernel<true><<<NS_TILES + GT_TILES, 256, 0, stream>>>(
            cat, uemb, weight, normsq, cat16, useragg);
    } else {
        prep_kernel<false><<<NS_TILES + GT_TILES, 256, 0, stream>>>(
            cat, uemb, weight, normsq, cat16, useragg);
    }
    bhist_kernel<<<256, 256, 0, stream>>>(head, iu, gcnt);
    bscan_kernel<<<1, 1024, 0, stream>>>(gcnt, hbase, ubase, cur);
    binning_kernel<<<256, 1024, 0, stream>>>(head, tail, etype, iu, ic, ival,
                                             cur, ebinned, nbinned);
    if (use16) {
        cat_bucket_agg<true><<<NB_H, 512, 0, stream>>>(
            ebinned, hbase, normsq, cat, cat16, weight, catagg);
        user_bucket_agg<true><<<NB_U, 512, 0, stream>>>(
            nbinned, ubase, cat, cat16, useragg);
    } else {
        cat_bucket_agg<false><<<NB_H, 512, 0, stream>>>(
            ebinned, hbase, normsq, cat, cat16, weight, catagg);
        user_bucket_agg<false><<<NB_U, 512, 0, stream>>>(
            nbinned, ubase, cat, cat16, useragg);
    }
}

// Round 9
// 283.808 us; speedup vs baseline: 2.0709x; 1.0578x over previous
//
#include <hip/hip_runtime.h>

#define N_CAT   100000
#define N_USERS 50000
#define DIM     64
#define N_RELM1 15
#define E_EDGES 1500000
#define NNZ_E   1500000

#define HPB   125           // heads per bucket
#define NB_H  800           // N_CAT / HPB
#define UPB   80            // users per bucket
#define NB_U  625           // N_USERS / UPB
#define NB_T  (NB_H + NB_U) // 1425
#define CAP_H 4096
#define CAP_U 4096

#define NS_TILES 1563       // ceil(N_CAT/64)
#define GT_TILES 782        // ceil(N_USERS/64)

#define NTL(p) __builtin_nontemporal_load(p)

__device__ __forceinline__ unsigned short f2bf(float v) {
    unsigned int ub = __float_as_uint(v);
    return (unsigned short)((ub + 0x7FFF + ((ub >> 16) & 1)) >> 16);
}

// K1: prep — tile-matmul normsq (no cross-lane), bf16 cat table, gating factors.
template <bool USE16>
__global__ void __launch_bounds__(256)
prep_kernel(const float* __restrict__ cat, const float* __restrict__ uemb,
            const float* __restrict__ weight,
            float* __restrict__ normsq, unsigned short* __restrict__ cat16,
            float* __restrict__ gfac) {
    int t = threadIdx.x;
    int lane = t & 63, wid = t >> 6;
    if (blockIdx.x < NS_TILES) {
        __shared__ float c2[64 * 65];
        __shared__ float w2t[64 * 16];   // [d][r] of w^2
        __shared__ float nsqT[16 * 64];  // [r][n]
        int nbase = blockIdx.x * 64;
        int nclamp = min(64, N_CAT - nbase);
        for (int i = t; i < 1024; i += 256) {
            int d = i >> 4, r = i & 15;
            float w = (r < N_RELM1) ? weight[r * 64 + d] : 0.f;
            w2t[i] = w * w;
        }
        for (int i = t; i < 4096; i += 256) {
            int row = i >> 6, d = i & 63;
            float v = (row < nclamp) ? cat[(size_t)(nbase + row) * 64 + d] : 0.f;
            c2[row * 65 + d] = v * v;
            if (USE16 && row < nclamp)
                cat16[(size_t)(nbase + row) * 64 + d] = f2bf(v);
        }
        __syncthreads();
        float a0 = 0, a1 = 0, a2 = 0, a3 = 0;
        int r0 = wid * 4;
#pragma unroll 8
        for (int d = 0; d < 64; ++d) {
            float c = c2[lane * 65 + d];
            float4 w4 = *(float4*)&w2t[d * 16 + r0];
            a0 += c * w4.x; a1 += c * w4.y; a2 += c * w4.z; a3 += c * w4.w;
        }
        nsqT[(r0 + 0) * 64 + lane] = a0;
        nsqT[(r0 + 1) * 64 + lane] = a1;
        nsqT[(r0 + 2) * 64 + lane] = a2;
        nsqT[(r0 + 3) * 64 + lane] = a3;
        __syncthreads();
        for (int i = t; i < nclamp * 15; i += 256) {
            int n = i / 15, r = i - n * 15;
            normsq[(size_t)(nbase + n) * 15 + r] = nsqT[r * 64 + n];
        }
    } else {
        __shared__ float ut[64 * 65];
        __shared__ float wt[64 * 16];   // [d][r]
        __shared__ float wrT[16 * 64];  // [r][d]
        __shared__ float st[64 * 16];   // scores [u][r]
        __shared__ float pt[64 * 16];   // probs  [u][r]
        int ub_ = (blockIdx.x - NS_TILES) * 64;
        int uclamp = min(64, N_USERS - ub_);
        for (int i = t; i < 1024; i += 256) {
            int d = i >> 4, r = i & 15;
            float w = (r < N_RELM1) ? weight[r * 64 + d] : 0.f;
            wt[i] = w;
            wrT[r * 64 + d] = w;
        }
        for (int i = t; i < 4096; i += 256) {
            int row = i >> 6, d = i & 63;
            ut[row * 65 + d] = (row < uclamp) ? uemb[(size_t)(ub_ + row) * 64 + d] : 0.f;
        }
        __syncthreads();
        float a0 = 0, a1 = 0, a2 = 0, a3 = 0;
        int r0 = wid * 4;
#pragma unroll 8
        for (int d = 0; d < 64; ++d) {
            float c = ut[lane * 65 + d];
            float4 w4 = *(float4*)&wt[d * 16 + r0];
            a0 += c * w4.x; a1 += c * w4.y; a2 += c * w4.z; a3 += c * w4.w;
        }
        st[lane * 16 + r0 + 0] = a0;
        st[lane * 16 + r0 + 1] = a1;
        st[lane * 16 + r0 + 2] = a2;
        st[lane * 16 + r0 + 3] = a3;
        __syncthreads();
        if (wid == 0) {
            float mx = -1e30f;
            float pv[N_RELM1];
#pragma unroll
            for (int r = 0; r < N_RELM1; ++r) mx = fmaxf(mx, st[lane * 16 + r]);
            float Z = 0.f;
#pragma unroll
            for (int r = 0; r < N_RELM1; ++r) { pv[r] = expf(st[lane * 16 + r] - mx); Z += pv[r]; }
            float inv = 1.f / Z;
#pragma unroll
            for (int r = 0; r < N_RELM1; ++r) pt[lane * 16 + r] = pv[r] * inv;
        }
        __syncthreads();
        for (int i = t; i < uclamp * 64; i += 256) {
            int u = i >> 6, d = i & 63;
            float g = 0.f;
#pragma unroll
            for (int r = 0; r < N_RELM1; ++r) g += pt[u * 16 + r] * wrT[r * 64 + d];
            gfac[(size_t)(ub_ + u) * 64 + d] = g;
        }
    }
}

// K2: bucket histogram
__global__ void bhist_kernel(const int* __restrict__ head, const int* __restrict__ iu,
                             int* __restrict__ gcnt) {
    __shared__ int cnt[NB_T];
    for (int i = threadIdx.x; i < NB_T; i += blockDim.x) cnt[i] = 0;
    __syncthreads();
    int stride = gridDim.x * blockDim.x;
    for (int e = blockIdx.x * blockDim.x + threadIdx.x; e < E_EDGES; e += stride) {
        atomicAdd(&cnt[NTL(&head[e]) / HPB], 1);
        atomicAdd(&cnt[NB_H + NTL(&iu[e]) / UPB], 1);
    }
    __syncthreads();
    for (int i = threadIdx.x; i < NB_T; i += blockDim.x)
        if (cnt[i]) atomicAdd(&gcnt[i], cnt[i]);
}

// K3: single-block scan of bucket counts
__global__ void bscan_kernel(const int* __restrict__ gcnt,
                             int* __restrict__ hbase, int* __restrict__ ubase,
                             int* __restrict__ cur) {
    __shared__ int s0[2048], s1[2048];
    int tid = threadIdx.x;
    for (int i = tid; i < 2048; i += 1024) s0[i] = (i < NB_T) ? gcnt[i] : 0;
    __syncthreads();
    int* a = s0; int* b = s1;
    for (int d = 1; d < 2048; d <<= 1) {
        for (int i = tid; i < 2048; i += 1024)
            b[i] = (i >= d) ? a[i] + a[i - d] : a[i];
        __syncthreads();
        int* t = a; a = b; b = t;
    }
    for (int i = tid; i < NB_T; i += 1024) {
        int excl = (i == 0) ? 0 : a[i - 1];
        if (i < NB_H) { hbase[i] = excl; cur[i] = excl; }
        else { int v = excl - E_EDGES; ubase[i - NB_H] = v; cur[i] = v; }
    }
    if (tid == 0) { hbase[NB_H] = E_EDGES; ubase[NB_U] = NNZ_E; }
}

// K4: one-pass binning
__global__ void __launch_bounds__(1024)
binning_kernel(const int* __restrict__ head, const int* __restrict__ tail,
               const int* __restrict__ etype,
               const int* __restrict__ iu, const int* __restrict__ ic,
               const float* __restrict__ ival,
               int* __restrict__ cur,
               int* __restrict__ ebinned, unsigned long long* __restrict__ nbinned) {
    __shared__ int cnt[NB_T];
    __shared__ int base[NB_T];
    int CH = (E_EDGES + gridDim.x - 1) / gridDim.x;
    int c0 = blockIdx.x * CH;
    int c1 = min(c0 + CH, E_EDGES);
    for (int i = threadIdx.x; i < NB_T; i += 1024) cnt[i] = 0;
    __syncthreads();
    for (int e = c0 + threadIdx.x; e < c1; e += 1024) {
        atomicAdd(&cnt[NTL(&head[e]) / HPB], 1);
        atomicAdd(&cnt[NB_H + NTL(&iu[e]) / UPB], 1);
    }
    __syncthreads();
    for (int i = threadIdx.x; i < NB_T; i += 1024) {
        int c = cnt[i];
        if (c) base[i] = atomicAdd(&cur[i], c);
        cnt[i] = 0;
    }
    __syncthreads();
    for (int e = c0 + threadIdx.x; e < c1; e += 1024) {
        int h = NTL(&head[e]);
        int b = h / HPB;
        int r = atomicAdd(&cnt[b], 1);
        int pk = ((h - b * HPB) << 21) | (NTL(&tail[e]) << 4) | (NTL(&etype[e]) - 1);
        ebinned[base[b] + r] = pk;
        int u = NTL(&iu[e]);
        int b2 = NB_H + u / UPB;
        int r2 = atomicAdd(&cnt[b2], 1);
        unsigned long long w0 = (unsigned int)(((u - (b2 - NB_H) * UPB) << 17) | NTL(&ic[e]));
        unsigned long long w1 = (unsigned int)__float_as_uint(NTL(&ival[e]));
        nbinned[base[b2] + r2] = (w1 << 32) | w0;
    }
}

// K5: counting sort + block-wide att/atomicMax + 2-edges-per-wave split gather
template <bool USE16>
__global__ void __launch_bounds__(512)
cat_bucket_agg(const int* __restrict__ ebinned, const int* __restrict__ hbase,
               const float* __restrict__ normsq, const float* __restrict__ catf,
               const unsigned short* __restrict__ cat16,
               const float* __restrict__ weight, float* __restrict__ catagg) {
    __shared__ int   sorted[CAP_H];
    __shared__ float wexp[CAP_H];
    __shared__ float2 wlds2[N_RELM1 * 32];
    __shared__ int cnt[HPB];
    __shared__ int ofs[HPB + 1];
    __shared__ unsigned int mxu[HPB];
    const unsigned int* cat16_2 = (const unsigned int*)cat16;
    const float2* catf_2 = (const float2*)catf;
    int b = blockIdx.x;
    int s0 = hbase[b], n = hbase[b + 1] - s0;
    for (int i = threadIdx.x; i < N_RELM1 * 32; i += 512)
        wlds2[i] = ((const float2*)weight)[i];
    for (int i = threadIdx.x; i < HPB; i += 512) { cnt[i] = 0; mxu[i] = 0u; }
    __syncthreads();
    for (int i = threadIdx.x; i < n; i += 512)
        atomicAdd(&cnt[ebinned[s0 + i] >> 21], 1);
    __syncthreads();
    if (threadIdx.x == 0) {
        int acc = 0;
        for (int i = 0; i < HPB; ++i) { ofs[i] = acc; acc += cnt[i]; }
        ofs[HPB] = acc;
    }
    __syncthreads();
    for (int i = threadIdx.x; i < HPB; i += 512) cnt[i] = 0;
    __syncthreads();
    for (int i = threadIdx.x; i < n; i += 512) {
        int pk = ebinned[s0 + i];
        int hl = pk >> 21;
        int r = atomicAdd(&cnt[hl], 1);
        sorted[ofs[hl] + r] = pk;
    }
    __syncthreads();
    // phase A: block-wide att + per-head atomicMax (att >= 0)
    for (int i = threadIdx.x; i < n; i += 512) {
        int pk = sorted[i];
        int hl = pk >> 21, tj = (pk >> 4) & 0x1FFFF, rj = pk & 15;
        int h = b * HPB + hl;
        float att = normsq[h * N_RELM1 + rj] * normsq[(size_t)tj * N_RELM1 + rj];
        wexp[i] = att;
        atomicMax(&mxu[hl], __float_as_uint(att));
    }
    __syncthreads();
    int wid = threadIdx.x >> 6, lane = threadIdx.x & 63;
    int sub = lane & 31, half = lane >> 5;
    for (int hl = wid; hl < HPB; hl += 8) {
        int h = b * HPB + hl;
        int e0 = ofs[hl], e1 = ofs[hl + 1];
        float m = __uint_as_float(mxu[hl]);
        float Z = 0.f;
        for (int t = e0 + lane; t < e1; t += 64) {
            float w = expf(wexp[t] - m);
            wexp[t] = w;
            Z += w;
        }
#pragma unroll
        for (int off = 1; off < 64; off <<= 1)
            Z += __shfl_xor(Z, off, 64);
        float ax = 0.f, ay = 0.f;
        for (int j = e0; j < e1; j += 8) {
#pragma unroll
            for (int k = 0; k < 4; ++k) {
                int idx = j + k * 2 + half;
                bool ok = idx < e1;
                idx = ok ? idx : e0;
                int pk = sorted[idx];
                float w = ok ? wexp[idx] : 0.f;
                int tj = (pk >> 4) & 0x1FFFF, rj = pk & 15;
                float c0, c1;
                if (USE16) {
                    unsigned int uv = cat16_2[(size_t)tj * 32 + sub];
                    c0 = __uint_as_float(uv << 16);
                    c1 = __uint_as_float(uv & 0xFFFF0000u);
                } else {
                    float2 cv = catf_2[(size_t)tj * 32 + sub];
                    c0 = cv.x; c1 = cv.y;
                }
                float2 wl = wlds2[rj * 32 + sub];
                ax += w * c0 * wl.x;
                ay += w * c1 * wl.y;
            }
        }
        ax += __shfl_xor(ax, 32, 64);
        ay += __shfl_xor(ay, 32, 64);
        if (lane < 32) {
            float invZ = (e1 > e0) ? 1.f / Z : 0.f;
            ((float2*)catagg)[(size_t)h * 32 + sub] = make_float2(ax * invZ, ay * invZ);
        }
    }
}

// K6: counting sort + 2-edges-per-wave split gather; gating factor from gfac
template <bool USE16>
__global__ void __launch_bounds__(512)
user_bucket_agg(const unsigned long long* __restrict__ nbinned,
                const int* __restrict__ ubase,
                const float* __restrict__ catf,
                const unsigned short* __restrict__ cat16,
                float* __restrict__ useragg) {
    __shared__ unsigned long long sorted[CAP_U];
    __shared__ int cnt[UPB];
    __shared__ int ofs[UPB + 1];
    const unsigned int* cat16_2 = (const unsigned int*)cat16;
    const float2* catf_2 = (const float2*)catf;
    int b = blockIdx.x;
    int s0 = ubase[b], n = ubase[b + 1] - s0;
    for (int i = threadIdx.x; i < UPB; i += 512) cnt[i] = 0;
    __syncthreads();
    for (int i = threadIdx.x; i < n; i += 512) {
        unsigned int w0 = (unsigned int)nbinned[s0 + i];
        atomicAdd(&cnt[w0 >> 17], 1);
    }
    __syncthreads();
    if (threadIdx.x == 0) {
        int acc = 0;
        for (int i = 0; i < UPB; ++i) { ofs[i] = acc; acc += cnt[i]; }
        ofs[UPB] = acc;
    }
    __syncthreads();
    for (int i = threadIdx.x; i < UPB; i += 512) cnt[i] = 0;
    __syncthreads();
    for (int i = threadIdx.x; i < n; i += 512) {
        unsigned long long pay = nbinned[s0 + i];
        int ul = ((unsigned int)pay) >> 17;
        int r = atomicAdd(&cnt[ul], 1);
        sorted[ofs[ul] + r] = pay;
    }
    __syncthreads();
    int wid = threadIdx.x >> 6, lane = threadIdx.x & 63;
    int sub = lane & 31, half = lane >> 5;
    for (int ul = wid; ul < UPB; ul += 8) {
        int u = b * UPB + ul;
        int e0 = ofs[ul], e1 = ofs[ul + 1];
        float ax = 0.f, ay = 0.f;
        for (int j = e0; j < e1; j += 8) {
#pragma unroll
            for (int k = 0; k < 4; ++k) {
                int idx = j + k * 2 + half;
                bool ok = idx < e1;
                idx = ok ? idx : e0;
                unsigned long long pay = sorted[idx];
                float v = ok ? __uint_as_float((unsigned int)(pay >> 32)) : 0.f;
                int c = (int)((unsigned int)pay & 0x1FFFFu);
                float c0, c1;
                if (USE16) {
                    unsigned int uv = cat16_2[(size_t)c * 32 + sub];
                    c0 = __uint_as_float(uv << 16);
                    c1 = __uint_as_float(uv & 0xFFFF0000u);
                } else {
                    float2 cv = catf_2[(size_t)c * 32 + sub];
                    c0 = cv.x; c1 = cv.y;
                }
                ax += v * c0;
                ay += v * c1;
            }
        }
        ax += __shfl_xor(ax, 32, 64);
        ay += __shfl_xor(ay, 32, 64);
        if (lane < 32) {
            float2 gf = ((float2*)useragg)[(size_t)u * 32 + sub];
            ((float2*)useragg)[(size_t)u * 32 + sub] =
                make_float2(ax * (1.f + gf.x), ay * (1.f + gf.y));
        }
    }
}

extern "C" void kernel_launch(void* const* d_in, const int* in_sizes, int n_in,
                              void* d_out, int out_size, void* d_ws, size_t ws_size,
                              hipStream_t stream) {
    const float* cat    = (const float*)d_in[0];
    const float* uemb   = (const float*)d_in[1];
    const int*   eidx   = (const int*)d_in[2];
    const int*   etype  = (const int*)d_in[3];
    const int*   iidx   = (const int*)d_in[4];
    const float* ival   = (const float*)d_in[5];
    const float* weight = (const float*)d_in[6];

    float* catagg  = (float*)d_out;
    float* useragg = (float*)d_out + (size_t)N_CAT * DIM;

    // workspace layout (4-byte words)
    int* ws = (int*)d_ws;
    float* normsq   = (float*)ws;                              // [0, 1.5M)
    int*   ebinned  = ws + 1500000;                            // [1.5M, 3M)
    unsigned long long* nbinned = (unsigned long long*)(ws + 3000000); // [3M, 6M)
    int*   gcnt     = ws + 6000000;                            // 1425
    int*   hbase    = ws + 6001425;                            // 801
    int*   ubase    = ws + 6002226;                            // 626
    int*   cur      = ws + 6002852;                            // 1425
    unsigned short* cat16 = (unsigned short*)(ws + 6004278);   // 6.4M ushorts
    const size_t NEED16 = (size_t)(6004278 + 3200000) * 4;
    bool use16 = ws_size >= NEED16;

    const int* head = eidx;
    const int* tail = eidx + E_EDGES;
    const int* iu   = iidx;
    const int* ic   = iidx + NNZ_E;

    hipMemsetAsync(gcnt, 0, (size_t)NB_T * sizeof(int), stream);

    if (use16) {
        prep_kernel<true><<<NS_TILES + GT_TILES, 256, 0, stream>>>(
            cat, uemb, weight, normsq, cat16, useragg);
    } else {
        prep_kernel<false><<<NS_TILES + GT_TILES, 256, 0, stream>>>(
            cat, uemb, weight, normsq, cat16, useragg);
    }
    bhist_kernel<<<256, 256, 0, stream>>>(head, iu, gcnt);
    bscan_kernel<<<1, 1024, 0, stream>>>(gcnt, hbase, ubase, cur);
    binning_kernel<<<256, 1024, 0, stream>>>(head, tail, etype, iu, ic, ival,
                                             cur, ebinned, nbinned);
    if (use16) {
        cat_bucket_agg<true><<<NB_H, 512, 0, stream>>>(
            ebinned, hbase, normsq, cat, cat16, weight, catagg);
        user_bucket_agg<true><<<NB_U, 512, 0, stream>>>(
            nbinned, ubase, cat, cat16, useragg);
    } else {
        cat_bucket_agg<false><<<NB_H, 512, 0, stream>>>(
            ebinned, hbase, normsq, cat, cat16, weight, catagg);
        user_bucket_agg<false><<<NB_U, 512, 0, stream>>>(
            nbinned, ubase, cat, cat16, useragg);
    }
}

// Round 10
// 242.188 us; speedup vs baseline: 2.4268x; 1.1719x over previous
//
#include <hip/hip_runtime.h>

#define N_CAT   100000
#define N_USERS 50000
#define DIM     64
#define N_RELM1 15
#define E_EDGES 1500000
#define NNZ_E   1500000

#define HPB   125           // heads per bucket
#define NB_H  800           // N_CAT / HPB
#define UPB   80            // users per bucket
#define NB_U  625           // N_USERS / UPB
#define NB_T  (NB_H + NB_U) // 1425
#define CAP8  3072          // shared payload slots in fused agg (max bucket ~2100/2650)

#define NS_TILES 1563       // ceil(N_CAT/64)
#define GT_TILES 782        // ceil(N_USERS/64)
#define HIST_BLKS 256

#define NTL(p) __builtin_nontemporal_load(p)

__device__ __forceinline__ unsigned short f2bf(float v) {
    unsigned int ub = __float_as_uint(v);
    return (unsigned short)((ub + 0x7FFF + ((ub >> 16) & 1)) >> 16);
}

// K1: prep — normsq tile-matmul + bf16 table + gating factors + bucket histogram
template <bool USE16>
__global__ void __launch_bounds__(256)
prep_kernel(const float* __restrict__ cat, const float* __restrict__ uemb,
            const float* __restrict__ weight,
            const int* __restrict__ head, const int* __restrict__ iu,
            float* __restrict__ normsq, unsigned short* __restrict__ cat16,
            float* __restrict__ gfac, int* __restrict__ gcnt) {
    __shared__ float smem[8320];
    int t = threadIdx.x;
    int lane = t & 63, wid = t >> 6;
    if (blockIdx.x < NS_TILES) {
        float* c2   = smem;          // 64*65
        float* w2t  = smem + 4160;   // 64*16 [d][r] of w^2
        float* nsqT = smem + 5184;   // 16*64 [r][n]
        int nbase = blockIdx.x * 64;
        int nclamp = min(64, N_CAT - nbase);
        for (int i = t; i < 1024; i += 256) {
            int d = i >> 4, r = i & 15;
            float w = (r < N_RELM1) ? weight[r * 64 + d] : 0.f;
            w2t[i] = w * w;
        }
        for (int i = t; i < 4096; i += 256) {
            int row = i >> 6, d = i & 63;
            float v = (row < nclamp) ? cat[(size_t)(nbase + row) * 64 + d] : 0.f;
            c2[row * 65 + d] = v * v;
            if (USE16 && row < nclamp)
                cat16[(size_t)(nbase + row) * 64 + d] = f2bf(v);
        }
        __syncthreads();
        float a0 = 0, a1 = 0, a2 = 0, a3 = 0;
        int r0 = wid * 4;
#pragma unroll 8
        for (int d = 0; d < 64; ++d) {
            float c = c2[lane * 65 + d];
            float4 w4 = *(float4*)&w2t[d * 16 + r0];
            a0 += c * w4.x; a1 += c * w4.y; a2 += c * w4.z; a3 += c * w4.w;
        }
        nsqT[(r0 + 0) * 64 + lane] = a0;
        nsqT[(r0 + 1) * 64 + lane] = a1;
        nsqT[(r0 + 2) * 64 + lane] = a2;
        nsqT[(r0 + 3) * 64 + lane] = a3;
        __syncthreads();
        for (int i = t; i < nclamp * 15; i += 256) {
            int n = i / 15, r = i - n * 15;
            normsq[(size_t)(nbase + n) * 15 + r] = nsqT[r * 64 + n];
        }
    } else if (blockIdx.x < NS_TILES + GT_TILES) {
        float* ut  = smem;          // 64*65
        float* wt  = smem + 4160;   // 64*16 [d][r]
        float* wrT = smem + 5184;   // 16*64 [r][d]
        float* st  = smem + 6208;   // 64*16 scores
        float* pt  = smem + 7232;   // 64*16 probs
        int ub_ = (blockIdx.x - NS_TILES) * 64;
        int uclamp = min(64, N_USERS - ub_);
        for (int i = t; i < 1024; i += 256) {
            int d = i >> 4, r = i & 15;
            float w = (r < N_RELM1) ? weight[r * 64 + d] : 0.f;
            wt[i] = w;
            wrT[r * 64 + d] = w;
        }
        for (int i = t; i < 4096; i += 256) {
            int row = i >> 6, d = i & 63;
            ut[row * 65 + d] = (row < uclamp) ? uemb[(size_t)(ub_ + row) * 64 + d] : 0.f;
        }
        __syncthreads();
        float a0 = 0, a1 = 0, a2 = 0, a3 = 0;
        int r0 = wid * 4;
#pragma unroll 8
        for (int d = 0; d < 64; ++d) {
            float c = ut[lane * 65 + d];
            float4 w4 = *(float4*)&wt[d * 16 + r0];
            a0 += c * w4.x; a1 += c * w4.y; a2 += c * w4.z; a3 += c * w4.w;
        }
        st[lane * 16 + r0 + 0] = a0;
        st[lane * 16 + r0 + 1] = a1;
        st[lane * 16 + r0 + 2] = a2;
        st[lane * 16 + r0 + 3] = a3;
        __syncthreads();
        if (wid == 0) {
            float mx = -1e30f;
            float pv[N_RELM1];
#pragma unroll
            for (int r = 0; r < N_RELM1; ++r) mx = fmaxf(mx, st[lane * 16 + r]);
            float Z = 0.f;
#pragma unroll
            for (int r = 0; r < N_RELM1; ++r) { pv[r] = expf(st[lane * 16 + r] - mx); Z += pv[r]; }
            float inv = 1.f / Z;
#pragma unroll
            for (int r = 0; r < N_RELM1; ++r) pt[lane * 16 + r] = pv[r] * inv;
        }
        __syncthreads();
        for (int i = t; i < uclamp * 64; i += 256) {
            int u = i >> 6, d = i & 63;
            float g = 0.f;
#pragma unroll
            for (int r = 0; r < N_RELM1; ++r) g += pt[u * 16 + r] * wrT[r * 64 + d];
            gfac[(size_t)(ub_ + u) * 64 + d] = g;
        }
    } else {
        // bucket histogram
        int* cnt = (int*)smem;  // NB_T
        for (int i = t; i < NB_T; i += 256) cnt[i] = 0;
        __syncthreads();
        int hb = blockIdx.x - NS_TILES - GT_TILES;
        int stride = HIST_BLKS * 256;
        for (int e = hb * 256 + t; e < E_EDGES; e += stride) {
            atomicAdd(&cnt[NTL(&head[e]) / HPB], 1);
            atomicAdd(&cnt[NB_H + NTL(&iu[e]) / UPB], 1);
        }
        __syncthreads();
        for (int i = t; i < NB_T; i += 256)
            if (cnt[i]) atomicAdd(&gcnt[i], cnt[i]);
    }
}

// K2: single-block scan of bucket counts
__global__ void bscan_kernel(const int* __restrict__ gcnt,
                             int* __restrict__ hbase, int* __restrict__ ubase,
                             int* __restrict__ cur) {
    __shared__ int s0[2048], s1[2048];
    int tid = threadIdx.x;
    for (int i = tid; i < 2048; i += 1024) s0[i] = (i < NB_T) ? gcnt[i] : 0;
    __syncthreads();
    int* a = s0; int* b = s1;
    for (int d = 1; d < 2048; d <<= 1) {
        for (int i = tid; i < 2048; i += 1024)
            b[i] = (i >= d) ? a[i] + a[i - d] : a[i];
        __syncthreads();
        int* t = a; a = b; b = t;
    }
    for (int i = tid; i < NB_T; i += 1024) {
        int excl = (i == 0) ? 0 : a[i - 1];
        if (i < NB_H) { hbase[i] = excl; cur[i] = excl; }
        else { int v = excl - E_EDGES; ubase[i - NB_H] = v; cur[i] = v; }
    }
    if (tid == 0) { hbase[NB_H] = E_EDGES; ubase[NB_U] = NNZ_E; }
}

// K3: one-pass binning
__global__ void __launch_bounds__(1024)
binning_kernel(const int* __restrict__ head, const int* __restrict__ tail,
               const int* __restrict__ etype,
               const int* __restrict__ iu, const int* __restrict__ ic,
               const float* __restrict__ ival,
               int* __restrict__ cur,
               int* __restrict__ ebinned, unsigned long long* __restrict__ nbinned) {
    __shared__ int cnt[NB_T];
    __shared__ int base[NB_T];
    int CH = (E_EDGES + gridDim.x - 1) / gridDim.x;
    int c0 = blockIdx.x * CH;
    int c1 = min(c0 + CH, E_EDGES);
    for (int i = threadIdx.x; i < NB_T; i += 1024) cnt[i] = 0;
    __syncthreads();
    for (int e = c0 + threadIdx.x; e < c1; e += 1024) {
        atomicAdd(&cnt[NTL(&head[e]) / HPB], 1);
        atomicAdd(&cnt[NB_H + NTL(&iu[e]) / UPB], 1);
    }
    __syncthreads();
    for (int i = threadIdx.x; i < NB_T; i += 1024) {
        int c = cnt[i];
        if (c) base[i] = atomicAdd(&cur[i], c);
        cnt[i] = 0;
    }
    __syncthreads();
    for (int e = c0 + threadIdx.x; e < c1; e += 1024) {
        int h = NTL(&head[e]);
        int b = h / HPB;
        int r = atomicAdd(&cnt[b], 1);
        int pk = ((h - b * HPB) << 21) | (NTL(&tail[e]) << 4) | (NTL(&etype[e]) - 1);
        ebinned[base[b] + r] = pk;
        int u = NTL(&iu[e]);
        int b2 = NB_H + u / UPB;
        int r2 = atomicAdd(&cnt[b2], 1);
        unsigned long long w0 = (unsigned int)(((u - (b2 - NB_H) * UPB) << 17) | NTL(&ic[e]));
        unsigned long long w1 = (unsigned int)__float_as_uint(NTL(&ival[e]));
        nbinned[base[b2] + r2] = (w1 << 32) | w0;
    }
}

// K4: fused agg — blocks [0,NB_H): cat softmax-agg; [NB_H,NB_T): user agg
template <bool USE16>
__global__ void __launch_bounds__(512)
fused_agg(const int* __restrict__ ebinned, const int* __restrict__ hbase,
          const unsigned long long* __restrict__ nbinned, const int* __restrict__ ubase,
          const float* __restrict__ normsq, const float* __restrict__ catf,
          const unsigned short* __restrict__ cat16,
          const float* __restrict__ weight,
          float* __restrict__ catagg, float* __restrict__ useragg) {
    __shared__ unsigned long long buf8[CAP8];   // cat: (w-bits<<32)|pk ; user: payload
    __shared__ float2 wlds2[N_RELM1 * 32];
    __shared__ int cnt[HPB];
    __shared__ int ofs[HPB + 1];
    __shared__ unsigned int mxu[HPB];
    __shared__ float Zs[HPB];
    const unsigned int* cat16_2 = (const unsigned int*)cat16;
    const float2* catf_2 = (const float2*)catf;
    int t = threadIdx.x;
    int wid = t >> 6, lane = t & 63;
    int sub = lane & 31, half = lane >> 5;

    if (blockIdx.x < NB_H) {
        int b = blockIdx.x;
        int s0 = hbase[b];
        int n = min(hbase[b + 1] - s0, CAP8);
        for (int i = t; i < N_RELM1 * 32; i += 512)
            wlds2[i] = ((const float2*)weight)[i];
        for (int i = t; i < HPB; i += 512) { cnt[i] = 0; mxu[i] = 0u; Zs[i] = 0.f; }
        __syncthreads();
        for (int i = t; i < n; i += 512)
            atomicAdd(&cnt[ebinned[s0 + i] >> 21], 1);
        __syncthreads();
        if (t == 0) {
            int acc = 0;
            for (int i = 0; i < HPB; ++i) { ofs[i] = acc; acc += cnt[i]; }
            ofs[HPB] = acc;
        }
        __syncthreads();
        for (int i = t; i < HPB; i += 512) cnt[i] = 0;
        __syncthreads();
        // sort-scatter + att + per-head max, fused
        for (int i = t; i < n; i += 512) {
            int pk = ebinned[s0 + i];
            int hl = pk >> 21, tj = (pk >> 4) & 0x1FFFF, rj = pk & 15;
            int h = b * HPB + hl;
            float att = normsq[h * N_RELM1 + rj] * normsq[(size_t)tj * N_RELM1 + rj];
            int r = atomicAdd(&cnt[hl], 1);
            buf8[ofs[hl] + r] = ((unsigned long long)__float_as_uint(att) << 32) | (unsigned int)pk;
            atomicMax(&mxu[hl], __float_as_uint(att));
        }
        __syncthreads();
        // block-wide exp + Z accumulate
        for (int i = t; i < n; i += 512) {
            unsigned long long pay = buf8[i];
            int hl = ((int)(unsigned int)pay) >> 21;
            float att = __uint_as_float((unsigned int)(pay >> 32));
            float w = expf(att - __uint_as_float(mxu[hl]));
            ((unsigned int*)buf8)[2 * i + 1] = __float_as_uint(w);
            atomicAdd(&Zs[hl], w);
        }
        __syncthreads();
        // per-wave gather: 2 edges per wave (half-split), single b64 broadcast
        for (int hl = wid; hl < HPB; hl += 8) {
            int h = b * HPB + hl;
            int e0 = ofs[hl], e1 = ofs[hl + 1];
            float invZ = (e1 > e0) ? 1.f / Zs[hl] : 0.f;
            float ax = 0.f, ay = 0.f;
            for (int j = e0; j < e1; j += 8) {
#pragma unroll
                for (int k = 0; k < 4; ++k) {
                    int idx = j + k * 2 + half;
                    bool ok = idx < e1;
                    idx = ok ? idx : e0;
                    unsigned long long pay = buf8[idx];
                    int pk = (int)(unsigned int)pay;
                    float w = ok ? __uint_as_float((unsigned int)(pay >> 32)) : 0.f;
                    int tj = (pk >> 4) & 0x1FFFF, rj = pk & 15;
                    float c0, c1;
                    if (USE16) {
                        unsigned int uv = cat16_2[(size_t)tj * 32 + sub];
                        c0 = __uint_as_float(uv << 16);
                        c1 = __uint_as_float(uv & 0xFFFF0000u);
                    } else {
                        float2 cv = catf_2[(size_t)tj * 32 + sub];
                        c0 = cv.x; c1 = cv.y;
                    }
                    float2 wl = wlds2[rj * 32 + sub];
                    ax += w * c0 * wl.x;
                    ay += w * c1 * wl.y;
                }
            }
            ax += __shfl_xor(ax, 32, 64);
            ay += __shfl_xor(ay, 32, 64);
            if (lane < 32)
                ((float2*)catagg)[(size_t)h * 32 + sub] = make_float2(ax * invZ, ay * invZ);
        }
    } else {
        int ub = blockIdx.x - NB_H;
        int s0 = ubase[ub];
        int n = min(ubase[ub + 1] - s0, CAP8);
        for (int i = t; i < UPB; i += 512) cnt[i] = 0;
        __syncthreads();
        for (int i = t; i < n; i += 512)
            atomicAdd(&cnt[((unsigned int)nbinned[s0 + i]) >> 17], 1);
        __syncthreads();
        if (t == 0) {
            int acc = 0;
            for (int i = 0; i < UPB; ++i) { ofs[i] = acc; acc += cnt[i]; }
            ofs[UPB] = acc;
        }
        __syncthreads();
        for (int i = t; i < UPB; i += 512) cnt[i] = 0;
        __syncthreads();
        for (int i = t; i < n; i += 512) {
            unsigned long long pay = nbinned[s0 + i];
            int ul = ((unsigned int)pay) >> 17;
            int r = atomicAdd(&cnt[ul], 1);
            buf8[ofs[ul] + r] = pay;
        }
        __syncthreads();
        for (int ul = wid; ul < UPB; ul += 8) {
            int u = ub * UPB + ul;
            int e0 = ofs[ul], e1 = ofs[ul + 1];
            float ax = 0.f, ay = 0.f;
            for (int j = e0; j < e1; j += 8) {
#pragma unroll
                for (int k = 0; k < 4; ++k) {
                    int idx = j + k * 2 + half;
                    bool ok = idx < e1;
                    idx = ok ? idx : e0;
                    unsigned long long pay = buf8[idx];
                    float v = ok ? __uint_as_float((unsigned int)(pay >> 32)) : 0.f;
                    int c = (int)((unsigned int)pay & 0x1FFFFu);
                    float c0, c1;
                    if (USE16) {
                        unsigned int uv = cat16_2[(size_t)c * 32 + sub];
                        c0 = __uint_as_float(uv << 16);
                        c1 = __uint_as_float(uv & 0xFFFF0000u);
                    } else {
                        float2 cv = catf_2[(size_t)c * 32 + sub];
                        c0 = cv.x; c1 = cv.y;
                    }
                    ax += v * c0;
                    ay += v * c1;
                }
            }
            ax += __shfl_xor(ax, 32, 64);
            ay += __shfl_xor(ay, 32, 64);
            if (lane < 32) {
                float2 gf = ((float2*)useragg)[(size_t)u * 32 + sub];
                ((float2*)useragg)[(size_t)u * 32 + sub] =
                    make_float2(ax * (1.f + gf.x), ay * (1.f + gf.y));
            }
        }
    }
}

extern "C" void kernel_launch(void* const* d_in, const int* in_sizes, int n_in,
                              void* d_out, int out_size, void* d_ws, size_t ws_size,
                              hipStream_t stream) {
    const float* cat    = (const float*)d_in[0];
    const float* uemb   = (const float*)d_in[1];
    const int*   eidx   = (const int*)d_in[2];
    const int*   etype  = (const int*)d_in[3];
    const int*   iidx   = (const int*)d_in[4];
    const float* ival   = (const float*)d_in[5];
    const float* weight = (const float*)d_in[6];

    float* catagg  = (float*)d_out;
    float* useragg = (float*)d_out + (size_t)N_CAT * DIM;

    // workspace layout (4-byte words)
    int* ws = (int*)d_ws;
    float* normsq   = (float*)ws;                              // [0, 1.5M)
    int*   ebinned  = ws + 1500000;                            // [1.5M, 3M)
    unsigned long long* nbinned = (unsigned long long*)(ws + 3000000); // [3M, 6M)
    int*   gcnt     = ws + 6000000;                            // 1425
    int*   hbase    = ws + 6001425;                            // 801
    int*   ubase    = ws + 6002226;                            // 626
    int*   cur      = ws + 6002852;                            // 1425
    unsigned short* cat16 = (unsigned short*)(ws + 6004278);   // 6.4M ushorts
    const size_t NEED16 = (size_t)(6004278 + 3200000) * 4;
    bool use16 = ws_size >= NEED16;

    const int* head = eidx;
    const int* tail = eidx + E_EDGES;
    const int* iu   = iidx;
    const int* ic   = iidx + NNZ_E;

    hipMemsetAsync(gcnt, 0, (size_t)NB_T * sizeof(int), stream);

    if (use16) {
        prep_kernel<true><<<NS_TILES + GT_TILES + HIST_BLKS, 256, 0, stream>>>(
            cat, uemb, weight, head, iu, normsq, cat16, useragg, gcnt);
    } else {
        prep_kernel<false><<<NS_TILES + GT_TILES + HIST_BLKS, 256, 0, stream>>>(
            cat, uemb, weight, head, iu, normsq, cat16, useragg, gcnt);
    }
    bscan_kernel<<<1, 1024, 0, stream>>>(gcnt, hbase, ubase, cur);
    binning_kernel<<<256, 1024, 0, stream>>>(head, tail, etype, iu, ic, ival,
                                             cur, ebinned, nbinned);
    if (use16) {
        fused_agg<true><<<NB_T, 512, 0, stream>>>(
            ebinned, hbase, nbinned, ubase, normsq, cat, cat16, weight, catagg, useragg);
    } else {
        fused_agg<false><<<NB_T, 512, 0, stream>>>(
            ebinned, hbase, nbinned, ubase, normsq, cat, cat16, weight, catagg, useragg);
    }
}

// Round 11
// 238.166 us; speedup vs baseline: 2.4678x; 1.0169x over previous
//
#include <hip/hip_runtime.h>

#define N_CAT   100000
#define N_USERS 50000
#define DIM     64
#define N_RELM1 15
#define E_EDGES 1500000
#define NNZ_E   1500000

#define HPB   125           // heads per bucket
#define NB_H  800           // N_CAT / HPB
#define UPB   80            // users per bucket
#define NB_U  625           // N_USERS / UPB
#define NB_T  (NB_H + NB_U) // 1425
#define CAP8  3072          // shared payload slots in fused agg

#define NS_TILES 1563       // ceil(N_CAT/64)
#define GT_TILES 782        // ceil(N_USERS/64)
#define HIST_BLKS 256

#define NTL(p) __builtin_nontemporal_load(p)

__device__ __forceinline__ unsigned short f2bf(float v) {
    unsigned int ub = __float_as_uint(v);
    return (unsigned short)((ub + 0x7FFF + ((ub >> 16) & 1)) >> 16);
}

// K1: prep — normsq tile-matmul + bf16 table + gating factors + bucket histogram
template <bool USE16>
__global__ void __launch_bounds__(256)
prep_kernel(const float* __restrict__ cat, const float* __restrict__ uemb,
            const float* __restrict__ weight,
            const int* __restrict__ head, const int* __restrict__ iu,
            float* __restrict__ normsq, unsigned short* __restrict__ cat16,
            float* __restrict__ gfac, int* __restrict__ gcnt) {
    __shared__ float smem[8320];
    int t = threadIdx.x;
    int lane = t & 63, wid = t >> 6;
    if (blockIdx.x < NS_TILES) {
        float* c2   = smem;          // 64*65
        float* w2t  = smem + 4160;   // 64*16 [d][r] of w^2
        float* nsqT = smem + 5184;   // 16*64 [r][n]
        int nbase = blockIdx.x * 64;
        int nclamp = min(64, N_CAT - nbase);
        for (int i = t; i < 1024; i += 256) {
            int d = i >> 4, r = i & 15;
            float w = (r < N_RELM1) ? weight[r * 64 + d] : 0.f;
            w2t[i] = w * w;
        }
        for (int i = t; i < 4096; i += 256) {
            int row = i >> 6, d = i & 63;
            float v = (row < nclamp) ? cat[(size_t)(nbase + row) * 64 + d] : 0.f;
            c2[row * 65 + d] = v * v;
            if (USE16 && row < nclamp)
                cat16[(size_t)(nbase + row) * 64 + d] = f2bf(v);
        }
        __syncthreads();
        float a0 = 0, a1 = 0, a2 = 0, a3 = 0;
        int r0 = wid * 4;
#pragma unroll 8
        for (int d = 0; d < 64; ++d) {
            float c = c2[lane * 65 + d];
            float4 w4 = *(float4*)&w2t[d * 16 + r0];
            a0 += c * w4.x; a1 += c * w4.y; a2 += c * w4.z; a3 += c * w4.w;
        }
        nsqT[(r0 + 0) * 64 + lane] = a0;
        nsqT[(r0 + 1) * 64 + lane] = a1;
        nsqT[(r0 + 2) * 64 + lane] = a2;
        nsqT[(r0 + 3) * 64 + lane] = a3;
        __syncthreads();
        for (int i = t; i < nclamp * 15; i += 256) {
            int n = i / 15, r = i - n * 15;
            normsq[(size_t)(nbase + n) * 15 + r] = nsqT[r * 64 + n];
        }
    } else if (blockIdx.x < NS_TILES + GT_TILES) {
        float* ut  = smem;          // 64*65
        float* wt  = smem + 4160;   // 64*16 [d][r]
        float* wrT = smem + 5184;   // 16*64 [r][d]
        float* st  = smem + 6208;   // 64*16 scores
        float* pt  = smem + 7232;   // 64*16 probs
        int ub_ = (blockIdx.x - NS_TILES) * 64;
        int uclamp = min(64, N_USERS - ub_);
        for (int i = t; i < 1024; i += 256) {
            int d = i >> 4, r = i & 15;
            float w = (r < N_RELM1) ? weight[r * 64 + d] : 0.f;
            wt[i] = w;
            wrT[r * 64 + d] = w;
        }
        for (int i = t; i < 4096; i += 256) {
            int row = i >> 6, d = i & 63;
            ut[row * 65 + d] = (row < uclamp) ? uemb[(size_t)(ub_ + row) * 64 + d] : 0.f;
        }
        __syncthreads();
        float a0 = 0, a1 = 0, a2 = 0, a3 = 0;
        int r0 = wid * 4;
#pragma unroll 8
        for (int d = 0; d < 64; ++d) {
            float c = ut[lane * 65 + d];
            float4 w4 = *(float4*)&wt[d * 16 + r0];
            a0 += c * w4.x; a1 += c * w4.y; a2 += c * w4.z; a3 += c * w4.w;
        }
        st[lane * 16 + r0 + 0] = a0;
        st[lane * 16 + r0 + 1] = a1;
        st[lane * 16 + r0 + 2] = a2;
        st[lane * 16 + r0 + 3] = a3;
        __syncthreads();
        if (wid == 0) {
            float mx = -1e30f;
            float pv[N_RELM1];
#pragma unroll
            for (int r = 0; r < N_RELM1; ++r) mx = fmaxf(mx, st[lane * 16 + r]);
            float Z = 0.f;
#pragma unroll
            for (int r = 0; r < N_RELM1; ++r) { pv[r] = expf(st[lane * 16 + r] - mx); Z += pv[r]; }
            float inv = 1.f / Z;
#pragma unroll
            for (int r = 0; r < N_RELM1; ++r) pt[lane * 16 + r] = pv[r] * inv;
        }
        __syncthreads();
        for (int i = t; i < uclamp * 64; i += 256) {
            int u = i >> 6, d = i & 63;
            float g = 0.f;
#pragma unroll
            for (int r = 0; r < N_RELM1; ++r) g += pt[u * 16 + r] * wrT[r * 64 + d];
            gfac[(size_t)(ub_ + u) * 64 + d] = g;
        }
    } else {
        int* cnt = (int*)smem;  // NB_T
        for (int i = t; i < NB_T; i += 256) cnt[i] = 0;
        __syncthreads();
        int hb = blockIdx.x - NS_TILES - GT_TILES;
        int stride = HIST_BLKS * 256;
        for (int e = hb * 256 + t; e < E_EDGES; e += stride) {
            atomicAdd(&cnt[NTL(&head[e]) / HPB], 1);
            atomicAdd(&cnt[NB_H + NTL(&iu[e]) / UPB], 1);
        }
        __syncthreads();
        for (int i = t; i < NB_T; i += 256)
            if (cnt[i]) atomicAdd(&gcnt[i], cnt[i]);
    }
}

// K2: wave-scan of bucket counts (3 barriers)
__global__ void __launch_bounds__(1024)
bscan_kernel(const int* __restrict__ gcnt,
             int* __restrict__ hbase, int* __restrict__ ubase,
             int* __restrict__ cur) {
    __shared__ int wtot[16];
    int t = threadIdx.x, lane = t & 63, wv = t >> 6;
    int i0 = 2 * t, i1 = 2 * t + 1;
    int c0 = (i0 < NB_T) ? gcnt[i0] : 0;
    int c1 = (i1 < NB_T) ? gcnt[i1] : 0;
    int s = c0 + c1;
    int incl = s;
#pragma unroll
    for (int d = 1; d < 64; d <<= 1) {
        int v = __shfl_up(incl, d, 64);
        if (lane >= d) incl += v;
    }
    if (lane == 63) wtot[wv] = incl;
    __syncthreads();
    int woff = 0;
#pragma unroll
    for (int w = 0; w < 16; ++w) {
        int x = wtot[w];
        if (w < wv) woff += x;
    }
    int excl = woff + incl - s;
    // element i0 prefix = excl; i1 prefix = excl + c0
    if (i0 < NB_T) {
        if (i0 < NB_H) { hbase[i0] = excl; cur[i0] = excl; }
        else { int v = excl - E_EDGES; ubase[i0 - NB_H] = v; cur[i0] = v; }
    }
    int e1 = excl + c0;
    if (i1 < NB_T) {
        if (i1 < NB_H) { hbase[i1] = e1; cur[i1] = e1; }
        else { int v = e1 - E_EDGES; ubase[i1 - NB_H] = v; cur[i1] = v; }
    }
    if (t == 0) { hbase[NB_H] = E_EDGES; ubase[NB_U] = NNZ_E; }
}

// K3: one-pass binning
__global__ void __launch_bounds__(1024)
binning_kernel(const int* __restrict__ head, const int* __restrict__ tail,
               const int* __restrict__ etype,
               const int* __restrict__ iu, const int* __restrict__ ic,
               const float* __restrict__ ival,
               int* __restrict__ cur,
               int* __restrict__ ebinned, unsigned long long* __restrict__ nbinned) {
    __shared__ int cnt[NB_T];
    __shared__ int base[NB_T];
    int CH = (E_EDGES + gridDim.x - 1) / gridDim.x;
    int c0 = blockIdx.x * CH;
    int c1 = min(c0 + CH, E_EDGES);
    for (int i = threadIdx.x; i < NB_T; i += 1024) cnt[i] = 0;
    __syncthreads();
    for (int e = c0 + threadIdx.x; e < c1; e += 1024) {
        atomicAdd(&cnt[NTL(&head[e]) / HPB], 1);
        atomicAdd(&cnt[NB_H + NTL(&iu[e]) / UPB], 1);
    }
    __syncthreads();
    for (int i = threadIdx.x; i < NB_T; i += 1024) {
        int c = cnt[i];
        if (c) base[i] = atomicAdd(&cur[i], c);
        cnt[i] = 0;
    }
    __syncthreads();
    for (int e = c0 + threadIdx.x; e < c1; e += 1024) {
        int h = NTL(&head[e]);
        int b = h / HPB;
        int r = atomicAdd(&cnt[b], 1);
        int pk = ((h - b * HPB) << 21) | (NTL(&tail[e]) << 4) | (NTL(&etype[e]) - 1);
        ebinned[base[b] + r] = pk;
        int u = NTL(&iu[e]);
        int b2 = NB_H + u / UPB;
        int r2 = atomicAdd(&cnt[b2], 1);
        unsigned long long w0 = (unsigned int)(((u - (b2 - NB_H) * UPB) << 17) | NTL(&ic[e]));
        unsigned long long w1 = (unsigned int)__float_as_uint(NTL(&ival[e]));
        nbinned[base[b2] + r2] = (w1 << 32) | w0;
    }
}

// K4: fused agg — blocks [0,NB_H): cat softmax-agg; [NB_H,NB_T): user agg
// quarter-split gather: 16 lanes per 128B row, 4 edges per wave concurrently
template <bool USE16>
__global__ void __launch_bounds__(512)
fused_agg(const int* __restrict__ ebinned, const int* __restrict__ hbase,
          const unsigned long long* __restrict__ nbinned, const int* __restrict__ ubase,
          const float* __restrict__ normsq, const float* __restrict__ catf,
          const unsigned short* __restrict__ cat16,
          const float* __restrict__ weight,
          float* __restrict__ catagg, float* __restrict__ useragg) {
    __shared__ unsigned long long buf8[CAP8];   // cat: (w-bits<<32)|pk ; user: payload
    __shared__ float4 wlds4[N_RELM1 * 16];
    __shared__ int cnt[HPB];
    __shared__ int ofs[HPB + 1];
    __shared__ unsigned int mxu[HPB];
    __shared__ float Zs[HPB];
    const uint2*  c16r = (const uint2*)cat16;
    const float4* cfr  = (const float4*)catf;
    int t = threadIdx.x;
    int wid = t >> 6, lane = t & 63;
    int qlane = lane & 15, qid = lane >> 4;

    if (blockIdx.x < NB_H) {
        int b = blockIdx.x;
        int s0 = hbase[b];
        int n = min(hbase[b + 1] - s0, CAP8);
        for (int i = t; i < N_RELM1 * 16; i += 512)
            wlds4[i] = ((const float4*)weight)[i];
        for (int i = t; i < HPB; i += 512) { cnt[i] = 0; mxu[i] = 0u; Zs[i] = 0.f; }
        __syncthreads();
        for (int i = t; i < n; i += 512)
            atomicAdd(&cnt[ebinned[s0 + i] >> 21], 1);
        __syncthreads();
        if (wid == 0) {  // wave-scan ofs (2 elems/lane, covers 0..127 >= HPB+1)
            int i0 = 2 * lane, i1 = 2 * lane + 1;
            int c0 = (i0 < HPB) ? cnt[i0] : 0;
            int c1 = (i1 < HPB) ? cnt[i1] : 0;
            int s = c0 + c1, incl = s;
#pragma unroll
            for (int d = 1; d < 64; d <<= 1) {
                int v = __shfl_up(incl, d, 64);
                if (lane >= d) incl += v;
            }
            int excl = incl - s;
            if (i0 <= HPB) ofs[i0] = excl;
            if (i1 <= HPB) ofs[i1] = excl + c0;
        }
        __syncthreads();
        for (int i = t; i < HPB; i += 512) cnt[i] = 0;
        __syncthreads();
        // sort-scatter + att + per-head max, fused
        for (int i = t; i < n; i += 512) {
            int pk = ebinned[s0 + i];
            int hl = pk >> 21, tj = (pk >> 4) & 0x1FFFF, rj = pk & 15;
            int h = b * HPB + hl;
            float att = normsq[h * N_RELM1 + rj] * normsq[(size_t)tj * N_RELM1 + rj];
            int r = atomicAdd(&cnt[hl], 1);
            buf8[ofs[hl] + r] = ((unsigned long long)__float_as_uint(att) << 32) | (unsigned int)pk;
            atomicMax(&mxu[hl], __float_as_uint(att));
        }
        __syncthreads();
        // block-wide exp + Z accumulate
        for (int i = t; i < n; i += 512) {
            unsigned long long pay = buf8[i];
            int hl = ((int)(unsigned int)pay) >> 21;
            float att = __uint_as_float((unsigned int)(pay >> 32));
            float w = expf(att - __uint_as_float(mxu[hl]));
            ((unsigned int*)buf8)[2 * i + 1] = __float_as_uint(w);
            atomicAdd(&Zs[hl], w);
        }
        __syncthreads();
        // quarter-split gather: 4 edges/wave, 16 edges per j-iteration
        for (int hl = wid; hl < HPB; hl += 8) {
            int h = b * HPB + hl;
            int e0 = ofs[hl], e1 = ofs[hl + 1];
            float invZ = (e1 > e0) ? 1.f / Zs[hl] : 0.f;
            float ax = 0.f, ay = 0.f, az = 0.f, aw = 0.f;
            for (int j = e0; j < e1; j += 16) {
#pragma unroll
                for (int k = 0; k < 4; ++k) {
                    int idx = j + k * 4 + qid;
                    bool ok = idx < e1;
                    idx = ok ? idx : e0;
                    unsigned long long pay = buf8[idx];
                    int pk = (int)(unsigned int)pay;
                    float w = ok ? __uint_as_float((unsigned int)(pay >> 32)) : 0.f;
                    int tj = (pk >> 4) & 0x1FFFF, rj = pk & 15;
                    float c0, c1, c2, c3;
                    if (USE16) {
                        uint2 uv = c16r[(size_t)tj * 16 + qlane];
                        c0 = __uint_as_float(uv.x << 16);
                        c1 = __uint_as_float(uv.x & 0xFFFF0000u);
                        c2 = __uint_as_float(uv.y << 16);
                        c3 = __uint_as_float(uv.y & 0xFFFF0000u);
                    } else {
                        float4 cv = cfr[(size_t)tj * 16 + qlane];
                        c0 = cv.x; c1 = cv.y; c2 = cv.z; c3 = cv.w;
                    }
                    float4 wl = wlds4[rj * 16 + qlane];
                    ax += w * c0 * wl.x;
                    ay += w * c1 * wl.y;
                    az += w * c2 * wl.z;
                    aw += w * c3 * wl.w;
                }
            }
            ax += __shfl_xor(ax, 16, 64); ax += __shfl_xor(ax, 32, 64);
            ay += __shfl_xor(ay, 16, 64); ay += __shfl_xor(ay, 32, 64);
            az += __shfl_xor(az, 16, 64); az += __shfl_xor(az, 32, 64);
            aw += __shfl_xor(aw, 16, 64); aw += __shfl_xor(aw, 32, 64);
            if (lane < 16)
                ((float4*)catagg)[(size_t)h * 16 + qlane] =
                    make_float4(ax * invZ, ay * invZ, az * invZ, aw * invZ);
        }
    } else {
        int ub = blockIdx.x - NB_H;
        int s0 = ubase[ub];
        int n = min(ubase[ub + 1] - s0, CAP8);
        for (int i = t; i < UPB; i += 512) cnt[i] = 0;
        __syncthreads();
        for (int i = t; i < n; i += 512)
            atomicAdd(&cnt[((unsigned int)nbinned[s0 + i]) >> 17], 1);
        __syncthreads();
        if (wid == 0) {  // wave-scan ofs (covers 0..127 >= UPB+1)
            int i0 = 2 * lane, i1 = 2 * lane + 1;
            int c0 = (i0 < UPB) ? cnt[i0] : 0;
            int c1 = (i1 < UPB) ? cnt[i1] : 0;
            int s = c0 + c1, incl = s;
#pragma unroll
            for (int d = 1; d < 64; d <<= 1) {
                int v = __shfl_up(incl, d, 64);
                if (lane >= d) incl += v;
            }
            int excl = incl - s;
            if (i0 <= UPB) ofs[i0] = excl;
            if (i1 <= UPB) ofs[i1] = excl + c0;
        }
        __syncthreads();
        for (int i = t; i < UPB; i += 512) cnt[i] = 0;
        __syncthreads();
        for (int i = t; i < n; i += 512) {
            unsigned long long pay = nbinned[s0 + i];
            int ul = ((unsigned int)pay) >> 17;
            int r = atomicAdd(&cnt[ul], 1);
            buf8[ofs[ul] + r] = pay;
        }
        __syncthreads();
        for (int ul = wid; ul < UPB; ul += 8) {
            int u = ub * UPB + ul;
            int e0 = ofs[ul], e1 = ofs[ul + 1];
            float ax = 0.f, ay = 0.f, az = 0.f, aw = 0.f;
            for (int j = e0; j < e1; j += 16) {
#pragma unroll
                for (int k = 0; k < 4; ++k) {
                    int idx = j + k * 4 + qid;
                    bool ok = idx < e1;
                    idx = ok ? idx : e0;
                    unsigned long long pay = buf8[idx];
                    float v = ok ? __uint_as_float((unsigned int)(pay >> 32)) : 0.f;
                    int c = (int)((unsigned int)pay & 0x1FFFFu);
                    float c0, c1, c2, c3;
                    if (USE16) {
                        uint2 uv = c16r[(size_t)c * 16 + qlane];
                        c0 = __uint_as_float(uv.x << 16);
                        c1 = __uint_as_float(uv.x & 0xFFFF0000u);
                        c2 = __uint_as_float(uv.y << 16);
                        c3 = __uint_as_float(uv.y & 0xFFFF0000u);
                    } else {
                        float4 cv = cfr[(size_t)c * 16 + qlane];
                        c0 = cv.x; c1 = cv.y; c2 = cv.z; c3 = cv.w;
                    }
                    ax += v * c0;
                    ay += v * c1;
                    az += v * c2;
                    aw += v * c3;
                }
            }
            ax += __shfl_xor(ax, 16, 64); ax += __shfl_xor(ax, 32, 64);
            ay += __shfl_xor(ay, 16, 64); ay += __shfl_xor(ay, 32, 64);
            az += __shfl_xor(az, 16, 64); az += __shfl_xor(az, 32, 64);
            aw += __shfl_xor(aw, 16, 64); aw += __shfl_xor(aw, 32, 64);
            if (lane < 16) {
                float4 gf = ((float4*)useragg)[(size_t)u * 16 + qlane];
                ((float4*)useragg)[(size_t)u * 16 + qlane] =
                    make_float4(ax * (1.f + gf.x), ay * (1.f + gf.y),
                                az * (1.f + gf.z), aw * (1.f + gf.w));
            }
        }
    }
}

extern "C" void kernel_launch(void* const* d_in, const int* in_sizes, int n_in,
                              void* d_out, int out_size, void* d_ws, size_t ws_size,
                              hipStream_t stream) {
    const float* cat    = (const float*)d_in[0];
    const float* uemb   = (const float*)d_in[1];
    const int*   eidx   = (const int*)d_in[2];
    const int*   etype  = (const int*)d_in[3];
    const int*   iidx   = (const int*)d_in[4];
    const float* ival   = (const float*)d_in[5];
    const float* weight = (const float*)d_in[6];

    float* catagg  = (float*)d_out;
    float* useragg = (float*)d_out + (size_t)N_CAT * DIM;

    // workspace layout (4-byte words)
    int* ws = (int*)d_ws;
    float* normsq   = (float*)ws;                              // [0, 1.5M)
    int*   ebinned  = ws + 1500000;                            // [1.5M, 3M)
    unsigned long long* nbinned = (unsigned long long*)(ws + 3000000); // [3M, 6M)
    int*   gcnt     = ws + 6000000;                            // 1425
    int*   hbase    = ws + 6001425;                            // 801
    int*   ubase    = ws + 6002226;                            // 626
    int*   cur      = ws + 6002852;                            // 1425
    unsigned short* cat16 = (unsigned short*)(ws + 6004278);   // 6.4M ushorts
    const size_t NEED16 = (size_t)(6004278 + 3200000) * 4;
    bool use16 = ws_size >= NEED16;

    const int* head = eidx;
    const int* tail = eidx + E_EDGES;
    const int* iu   = iidx;
    const int* ic   = iidx + NNZ_E;

    hipMemsetAsync(gcnt, 0, (size_t)NB_T * sizeof(int), stream);

    if (use16) {
        prep_kernel<true><<<NS_TILES + GT_TILES + HIST_BLKS, 256, 0, stream>>>(
            cat, uemb, weight, head, iu, normsq, cat16, useragg, gcnt);
    } else {
        prep_kernel<false><<<NS_TILES + GT_TILES + HIST_BLKS, 256, 0, stream>>>(
            cat, uemb, weight, head, iu, normsq, cat16, useragg, gcnt);
    }
    bscan_kernel<<<1, 1024, 0, stream>>>(gcnt, hbase, ubase, cur);
    binning_kernel<<<256, 1024, 0, stream>>>(head, tail, etype, iu, ic, ival,
                                             cur, ebinned, nbinned);
    if (use16) {
        fused_agg<true><<<NB_T, 512, 0, stream>>>(
            ebinned, hbase, nbinned, ubase, normsq, cat, cat16, weight, catagg, useragg);
    } else {
        fused_agg<false><<<NB_T, 512, 0, stream>>>(
            ebinned, hbase, nbinned, ubase, normsq, cat, cat16, weight, catagg, useragg);
    }
}

// Round 12
// 203.882 us; speedup vs baseline: 2.8827x; 1.1682x over previous
//
#include <hip/hip_runtime.h>

#define N_CAT   100000
#define N_USERS 50000
#define DIM     64
#define N_RELM1 15
#define E_EDGES 1500000
#define NNZ_E   1500000

#define HPB   125           // heads per bucket
#define NB_H  800           // N_CAT / HPB
#define UPB   80            // users per bucket
#define NB_U  625           // N_USERS / UPB
#define NB_T  (NB_H + NB_U) // 1425
#define CAP8  3072          // shared payload slots in fused agg

#define NS_TILES 1563       // ceil(N_CAT/64)
#define GT_TILES 782        // ceil(N_USERS/64)
#define HIST_BLKS 256

#define BIN_BLKS 256
#define BIN_CH   5860       // ceil(E_EDGES / BIN_BLKS)

#define NTL(p) __builtin_nontemporal_load(p)

__device__ __forceinline__ unsigned short f2bf(float v) {
    unsigned int ub = __float_as_uint(v);
    return (unsigned short)((ub + 0x7FFF + ((ub >> 16) & 1)) >> 16);
}

// K1: prep — normsq tile-matmul + bf16 table + gating factors + bucket histogram
template <bool USE16>
__global__ void __launch_bounds__(256)
prep_kernel(const float* __restrict__ cat, const float* __restrict__ uemb,
            const float* __restrict__ weight,
            const int* __restrict__ head, const int* __restrict__ iu,
            float* __restrict__ normsq, unsigned short* __restrict__ cat16,
            float* __restrict__ gfac, int* __restrict__ gcnt) {
    __shared__ float smem[8320];
    int t = threadIdx.x;
    int lane = t & 63, wid = t >> 6;
    if (blockIdx.x < NS_TILES) {
        float* c2   = smem;          // 64*65
        float* w2t  = smem + 4160;   // 64*16 [d][r] of w^2
        float* nsqT = smem + 5184;   // 16*64 [r][n]
        int nbase = blockIdx.x * 64;
        int nclamp = min(64, N_CAT - nbase);
        for (int i = t; i < 1024; i += 256) {
            int d = i >> 4, r = i & 15;
            float w = (r < N_RELM1) ? weight[r * 64 + d] : 0.f;
            w2t[i] = w * w;
        }
        for (int i = t; i < 4096; i += 256) {
            int row = i >> 6, d = i & 63;
            float v = (row < nclamp) ? cat[(size_t)(nbase + row) * 64 + d] : 0.f;
            c2[row * 65 + d] = v * v;
            if (USE16 && row < nclamp)
                cat16[(size_t)(nbase + row) * 64 + d] = f2bf(v);
        }
        __syncthreads();
        float a0 = 0, a1 = 0, a2 = 0, a3 = 0;
        int r0 = wid * 4;
#pragma unroll 8
        for (int d = 0; d < 64; ++d) {
            float c = c2[lane * 65 + d];
            float4 w4 = *(float4*)&w2t[d * 16 + r0];
            a0 += c * w4.x; a1 += c * w4.y; a2 += c * w4.z; a3 += c * w4.w;
        }
        nsqT[(r0 + 0) * 64 + lane] = a0;
        nsqT[(r0 + 1) * 64 + lane] = a1;
        nsqT[(r0 + 2) * 64 + lane] = a2;
        nsqT[(r0 + 3) * 64 + lane] = a3;
        __syncthreads();
        for (int i = t; i < nclamp * 15; i += 256) {
            int n = i / 15, r = i - n * 15;
            normsq[(size_t)(nbase + n) * 15 + r] = nsqT[r * 64 + n];
        }
    } else if (blockIdx.x < NS_TILES + GT_TILES) {
        float* ut  = smem;          // 64*65
        float* wt  = smem + 4160;   // 64*16 [d][r]
        float* wrT = smem + 5184;   // 16*64 [r][d]
        float* st  = smem + 6208;   // 64*16 scores
        float* pt  = smem + 7232;   // 64*16 probs
        int ub_ = (blockIdx.x - NS_TILES) * 64;
        int uclamp = min(64, N_USERS - ub_);
        for (int i = t; i < 1024; i += 256) {
            int d = i >> 4, r = i & 15;
            float w = (r < N_RELM1) ? weight[r * 64 + d] : 0.f;
            wt[i] = w;
            wrT[r * 64 + d] = w;
        }
        for (int i = t; i < 4096; i += 256) {
            int row = i >> 6, d = i & 63;
            ut[row * 65 + d] = (row < uclamp) ? uemb[(size_t)(ub_ + row) * 64 + d] : 0.f;
        }
        __syncthreads();
        float a0 = 0, a1 = 0, a2 = 0, a3 = 0;
        int r0 = wid * 4;
#pragma unroll 8
        for (int d = 0; d < 64; ++d) {
            float c = ut[lane * 65 + d];
            float4 w4 = *(float4*)&wt[d * 16 + r0];
            a0 += c * w4.x; a1 += c * w4.y; a2 += c * w4.z; a3 += c * w4.w;
        }
        st[lane * 16 + r0 + 0] = a0;
        st[lane * 16 + r0 + 1] = a1;
        st[lane * 16 + r0 + 2] = a2;
        st[lane * 16 + r0 + 3] = a3;
        __syncthreads();
        if (wid == 0) {
            float mx = -1e30f;
            float pv[N_RELM1];
#pragma unroll
            for (int r = 0; r < N_RELM1; ++r) mx = fmaxf(mx, st[lane * 16 + r]);
            float Z = 0.f;
#pragma unroll
            for (int r = 0; r < N_RELM1; ++r) { pv[r] = expf(st[lane * 16 + r] - mx); Z += pv[r]; }
            float inv = 1.f / Z;
#pragma unroll
            for (int r = 0; r < N_RELM1; ++r) pt[lane * 16 + r] = pv[r] * inv;
        }
        __syncthreads();
        for (int i = t; i < uclamp * 64; i += 256) {
            int u = i >> 6, d = i & 63;
            float g = 0.f;
#pragma unroll
            for (int r = 0; r < N_RELM1; ++r) g += pt[u * 16 + r] * wrT[r * 64 + d];
            gfac[(size_t)(ub_ + u) * 64 + d] = g;
        }
    } else {
        int* cnt = (int*)smem;  // NB_T
        for (int i = t; i < NB_T; i += 256) cnt[i] = 0;
        __syncthreads();
        int hb = blockIdx.x - NS_TILES - GT_TILES;
        int stride = HIST_BLKS * 256;
        const unsigned long long* h2 = (const unsigned long long*)head;
        const unsigned long long* u2 = (const unsigned long long*)iu;
        for (int e = hb * 256 + t; e < E_EDGES / 2; e += stride) {
            unsigned long long hv = NTL(&h2[e]);
            atomicAdd(&cnt[((int)hv) / HPB], 1);
            atomicAdd(&cnt[((int)(hv >> 32)) / HPB], 1);
            unsigned long long uv = NTL(&u2[e]);
            atomicAdd(&cnt[NB_H + ((int)uv) / UPB], 1);
            atomicAdd(&cnt[NB_H + ((int)(uv >> 32)) / UPB], 1);
        }
        __syncthreads();
        for (int i = t; i < NB_T; i += 256)
            if (cnt[i]) atomicAdd(&gcnt[i], cnt[i]);
    }
}

// K2: wave-scan of bucket counts
__global__ void __launch_bounds__(1024)
bscan_kernel(const int* __restrict__ gcnt,
             int* __restrict__ hbase, int* __restrict__ ubase,
             int* __restrict__ cur) {
    __shared__ int wtot[16];
    int t = threadIdx.x, lane = t & 63, wv = t >> 6;
    int i0 = 2 * t, i1 = 2 * t + 1;
    int c0 = (i0 < NB_T) ? gcnt[i0] : 0;
    int c1 = (i1 < NB_T) ? gcnt[i1] : 0;
    int s = c0 + c1;
    int incl = s;
#pragma unroll
    for (int d = 1; d < 64; d <<= 1) {
        int v = __shfl_up(incl, d, 64);
        if (lane >= d) incl += v;
    }
    if (lane == 63) wtot[wv] = incl;
    __syncthreads();
    int woff = 0;
#pragma unroll
    for (int w = 0; w < 16; ++w) {
        int x = wtot[w];
        if (w < wv) woff += x;
    }
    int excl = woff + incl - s;
    if (i0 < NB_T) {
        if (i0 < NB_H) { hbase[i0] = excl; cur[i0] = excl; }
        else { int v = excl - E_EDGES; ubase[i0 - NB_H] = v; cur[i0] = v; }
    }
    int e1 = excl + c0;
    if (i1 < NB_T) {
        if (i1 < NB_H) { hbase[i1] = e1; cur[i1] = e1; }
        else { int v = e1 - E_EDGES; ubase[i1 - NB_H] = v; cur[i1] = v; }
    }
    if (t == 0) { hbase[NB_H] = E_EDGES; ubase[NB_U] = NNZ_E; }
}

// block-wide exclusive scan of cnt[0..NB_T) into lofs, plus global reservation
__device__ __forceinline__ void scan_reserve(int* __restrict__ cnt, int* __restrict__ lofs,
                                             int* __restrict__ gbase, int* __restrict__ cur,
                                             int* __restrict__ wtot) {
    int t = threadIdx.x, lane = t & 63, wv = t >> 6;
    int i0 = 2 * t, i1 = 2 * t + 1;
    int a0 = (i0 < NB_T) ? cnt[i0] : 0;
    int a1 = (i1 < NB_T) ? cnt[i1] : 0;
    int s = a0 + a1, incl = s;
#pragma unroll
    for (int d = 1; d < 64; d <<= 1) {
        int v = __shfl_up(incl, d, 64);
        if (lane >= d) incl += v;
    }
    if (lane == 63) wtot[wv] = incl;
    __syncthreads();
    int woff = 0;
#pragma unroll
    for (int w = 0; w < 16; ++w) { int x = wtot[w]; if (w < wv) woff += x; }
    int excl = woff + incl - s;
    if (i0 < NB_T) lofs[i0] = excl;
    if (i1 < NB_T) lofs[i1] = excl + a0;
    for (int i = t; i < NB_T; i += 1024) {
        int c = cnt[i];
        gbase[i] = c ? atomicAdd(&cur[i], c) : 0;
    }
    __syncthreads();
}

// K3: binning with LDS write-combining (count -> reserve -> LDS counting sort -> run flush)
__global__ void __launch_bounds__(1024)
binning_kernel(const int* __restrict__ head, const int* __restrict__ tail,
               const int* __restrict__ etype,
               const int* __restrict__ iu, const int* __restrict__ ic,
               const float* __restrict__ ival,
               int* __restrict__ cur,
               int* __restrict__ ebinned, unsigned long long* __restrict__ nbinned) {
    __shared__ int cnt[NB_T];
    __shared__ int lofs[NB_T];
    __shared__ int gbase[NB_T];
    __shared__ int wtot[16];
    __shared__ int stage[BIN_CH];               // 23.4 KB (cat pk / user int2 half-chunks)
    __shared__ unsigned short sbk[BIN_CH];      // bucket id per slot
    int t = threadIdx.x;
    int c0 = blockIdx.x * BIN_CH;
    int c1 = min(c0 + BIN_CH, E_EDGES);

    // ---- CAT edges ----
    for (int i = t; i < NB_T; i += 1024) cnt[i] = 0;
    __syncthreads();
    for (int e = c0 + t; e < c1; e += 1024)
        atomicAdd(&cnt[NTL(&head[e]) / HPB], 1);
    __syncthreads();
    scan_reserve(cnt, lofs, gbase, cur, wtot);
    for (int i = t; i < NB_T; i += 1024) cnt[i] = 0;
    __syncthreads();
    for (int e = c0 + t; e < c1; e += 1024) {
        int h = NTL(&head[e]);
        int b = h / HPB;
        int r = atomicAdd(&cnt[b], 1);
        int slot = lofs[b] + r;
        stage[slot] = ((h - b * HPB) << 21) | (NTL(&tail[e]) << 4) | (NTL(&etype[e]) - 1);
        sbk[slot] = (unsigned short)b;
    }
    __syncthreads();
    int cn = c1 - c0;
    for (int s = t; s < cn; s += 1024) {
        int bk = sbk[s];
        ebinned[gbase[bk] + (s - lofs[bk])] = stage[s];
    }
    __syncthreads();

    // ---- USER nnz: two half-chunks (8B payload staged as int2) ----
    int2* stage2 = (int2*)stage;                // BIN_CH/2 int2 slots
    int2* nb2 = (int2*)nbinned;
#pragma unroll 1
    for (int half = 0; half < 2; ++half) {
        int h0 = c0 + half * (BIN_CH / 2);
        int h1 = min(h0 + BIN_CH / 2, E_EDGES);
        for (int i = t; i < NB_T; i += 1024) cnt[i] = 0;
        __syncthreads();
        for (int e = h0 + t; e < h1; e += 1024)
            atomicAdd(&cnt[NB_H + NTL(&iu[e]) / UPB], 1);
        __syncthreads();
        scan_reserve(cnt, lofs, gbase, cur, wtot);
        for (int i = t; i < NB_T; i += 1024) cnt[i] = 0;
        __syncthreads();
        for (int e = h0 + t; e < h1; e += 1024) {
            int u = NTL(&iu[e]);
            int b = NB_H + u / UPB;
            int r = atomicAdd(&cnt[b], 1);
            int slot = lofs[b] + r;
            stage2[slot] = make_int2(((u - (b - NB_H) * UPB) << 17) | NTL(&ic[e]),
                                     __float_as_int(NTL(&ival[e])));
            sbk[slot] = (unsigned short)b;
        }
        __syncthreads();
        int hn = h1 - h0;
        for (int s = t; s < hn; s += 1024) {
            int bk = sbk[s];
            nb2[gbase[bk] + (s - lofs[bk])] = stage2[s];
        }
        __syncthreads();
    }
}

// K4: fused agg — blocks [0,NB_H): cat softmax-agg; [NB_H,NB_T): user agg
template <bool USE16>
__global__ void __launch_bounds__(512)
fused_agg(const int* __restrict__ ebinned, const int* __restrict__ hbase,
          const unsigned long long* __restrict__ nbinned, const int* __restrict__ ubase,
          const float* __restrict__ normsq, const float* __restrict__ catf,
          const unsigned short* __restrict__ cat16,
          const float* __restrict__ weight,
          float* __restrict__ catagg, float* __restrict__ useragg) {
    __shared__ unsigned long long buf8[CAP8];   // cat: (w-bits<<32)|pk ; user: payload
    __shared__ float4 wlds4[N_RELM1 * 16];
    __shared__ float hn[HPB * N_RELM1];         // block's normsq[h] slice
    __shared__ int cnt[HPB];
    __shared__ int ofs[HPB + 1];
    __shared__ unsigned int mxu[HPB];
    __shared__ float Zs[HPB];
    const uint2*  c16r = (const uint2*)cat16;
    const float4* cfr  = (const float4*)catf;
    int t = threadIdx.x;
    int wid = t >> 6, lane = t & 63;
    int qlane = lane & 15, qid = lane >> 4;

    if (blockIdx.x < NB_H) {
        int b = blockIdx.x;
        int s0 = hbase[b];
        int n = min(hbase[b + 1] - s0, CAP8);
        for (int i = t; i < N_RELM1 * 16; i += 512)
            wlds4[i] = ((const float4*)weight)[i];
        for (int i = t; i < HPB * N_RELM1; i += 512)
            hn[i] = normsq[(size_t)b * HPB * N_RELM1 + i];
        for (int i = t; i < HPB; i += 512) { cnt[i] = 0; mxu[i] = 0u; Zs[i] = 0.f; }
        __syncthreads();
        for (int i = t; i < n; i += 512)
            atomicAdd(&cnt[ebinned[s0 + i] >> 21], 1);
        __syncthreads();
        if (wid == 0) {  // wave-scan ofs
            int i0 = 2 * lane, i1 = 2 * lane + 1;
            int c0 = (i0 < HPB) ? cnt[i0] : 0;
            int c1 = (i1 < HPB) ? cnt[i1] : 0;
            int s = c0 + c1, incl = s;
#pragma unroll
            for (int d = 1; d < 64; d <<= 1) {
                int v = __shfl_up(incl, d, 64);
                if (lane >= d) incl += v;
            }
            int excl = incl - s;
            if (i0 <= HPB) ofs[i0] = excl;
            if (i1 <= HPB) ofs[i1] = excl + c0;
        }
        __syncthreads();
        for (int i = t; i < HPB; i += 512) cnt[i] = 0;
        __syncthreads();
        // sort-scatter + att + per-head max, fused
        for (int i = t; i < n; i += 512) {
            int pk = ebinned[s0 + i];
            int hl = pk >> 21, tj = (pk >> 4) & 0x1FFFF, rj = pk & 15;
            float att = hn[hl * N_RELM1 + rj] * normsq[(size_t)tj * N_RELM1 + rj];
            int r = atomicAdd(&cnt[hl], 1);
            buf8[ofs[hl] + r] = ((unsigned long long)__float_as_uint(att) << 32) | (unsigned int)pk;
            atomicMax(&mxu[hl], __float_as_uint(att));
        }
        __syncthreads();
        // block-wide exp + Z accumulate
        for (int i = t; i < n; i += 512) {
            unsigned long long pay = buf8[i];
            int hl = ((int)(unsigned int)pay) >> 21;
            float att = __uint_as_float((unsigned int)(pay >> 32));
            float w = expf(att - __uint_as_float(mxu[hl]));
            ((unsigned int*)buf8)[2 * i + 1] = __float_as_uint(w);
            atomicAdd(&Zs[hl], w);
        }
        __syncthreads();
        // quarter-split gather: 4 edges/wave, 16 edges per j-iteration
        for (int hl = wid; hl < HPB; hl += 8) {
            int h = b * HPB + hl;
            int e0 = ofs[hl], e1 = ofs[hl + 1];
            float invZ = (e1 > e0) ? 1.f / Zs[hl] : 0.f;
            float ax = 0.f, ay = 0.f, az = 0.f, aw = 0.f;
            for (int j = e0; j < e1; j += 16) {
#pragma unroll
                for (int k = 0; k < 4; ++k) {
                    int idx = j + k * 4 + qid;
                    bool ok = idx < e1;
                    idx = ok ? idx : e0;
                    unsigned long long pay = buf8[idx];
                    int pk = (int)(unsigned int)pay;
                    float w = ok ? __uint_as_float((unsigned int)(pay >> 32)) : 0.f;
                    int tj = (pk >> 4) & 0x1FFFF, rj = pk & 15;
                    float c0, c1, c2, c3;
                    if (USE16) {
                        uint2 uv = c16r[(size_t)tj * 16 + qlane];
                        c0 = __uint_as_float(uv.x << 16);
                        c1 = __uint_as_float(uv.x & 0xFFFF0000u);
                        c2 = __uint_as_float(uv.y << 16);
                        c3 = __uint_as_float(uv.y & 0xFFFF0000u);
                    } else {
                        float4 cv = cfr[(size_t)tj * 16 + qlane];
                        c0 = cv.x; c1 = cv.y; c2 = cv.z; c3 = cv.w;
                    }
                    float4 wl = wlds4[rj * 16 + qlane];
                    ax += w * c0 * wl.x;
                    ay += w * c1 * wl.y;
                    az += w * c2 * wl.z;
                    aw += w * c3 * wl.w;
                }
            }
            ax += __shfl_xor(ax, 16, 64); ax += __shfl_xor(ax, 32, 64);
            ay += __shfl_xor(ay, 16, 64); ay += __shfl_xor(ay, 32, 64);
            az += __shfl_xor(az, 16, 64); az += __shfl_xor(az, 32, 64);
            aw += __shfl_xor(aw, 16, 64); aw += __shfl_xor(aw, 32, 64);
            if (lane < 16)
                ((float4*)catagg)[(size_t)h * 16 + qlane] =
                    make_float4(ax * invZ, ay * invZ, az * invZ, aw * invZ);
        }
    } else {
        int ub = blockIdx.x - NB_H;
        int s0 = ubase[ub];
        int n = min(ubase[ub + 1] - s0, CAP8);
        for (int i = t; i < UPB; i += 512) cnt[i] = 0;
        __syncthreads();
        for (int i = t; i < n; i += 512)
            atomicAdd(&cnt[((unsigned int)nbinned[s0 + i]) >> 17], 1);
        __syncthreads();
        if (wid == 0) {
            int i0 = 2 * lane, i1 = 2 * lane + 1;
            int c0 = (i0 < UPB) ? cnt[i0] : 0;
            int c1 = (i1 < UPB) ? cnt[i1] : 0;
            int s = c0 + c1, incl = s;
#pragma unroll
            for (int d = 1; d < 64; d <<= 1) {
                int v = __shfl_up(incl, d, 64);
                if (lane >= d) incl += v;
            }
            int excl = incl - s;
            if (i0 <= UPB) ofs[i0] = excl;
            if (i1 <= UPB) ofs[i1] = excl + c0;
        }
        __syncthreads();
        for (int i = t; i < UPB; i += 512) cnt[i] = 0;
        __syncthreads();
        for (int i = t; i < n; i += 512) {
            unsigned long long pay = nbinned[s0 + i];
            int ul = ((unsigned int)pay) >> 17;
            int r = atomicAdd(&cnt[ul], 1);
            buf8[ofs[ul] + r] = pay;
        }
        __syncthreads();
        // 8-deep unrolled gather: 32 edges per j-iteration
        for (int ul = wid; ul < UPB; ul += 8) {
            int u = ub * UPB + ul;
            int e0 = ofs[ul], e1 = ofs[ul + 1];
            float ax = 0.f, ay = 0.f, az = 0.f, aw = 0.f;
            for (int j = e0; j < e1; j += 32) {
#pragma unroll
                for (int k = 0; k < 8; ++k) {
                    int idx = j + k * 4 + qid;
                    bool ok = idx < e1;
                    idx = ok ? idx : e0;
                    unsigned long long pay = buf8[idx];
                    float v = ok ? __uint_as_float((unsigned int)(pay >> 32)) : 0.f;
                    int c = (int)((unsigned int)pay & 0x1FFFFu);
                    float c0, c1, c2, c3;
                    if (USE16) {
                        uint2 uv = c16r[(size_t)c * 16 + qlane];
                        c0 = __uint_as_float(uv.x << 16);
                        c1 = __uint_as_float(uv.x & 0xFFFF0000u);
                        c2 = __uint_as_float(uv.y << 16);
                        c3 = __uint_as_float(uv.y & 0xFFFF0000u);
                    } else {
                        float4 cv = cfr[(size_t)c * 16 + qlane];
                        c0 = cv.x; c1 = cv.y; c2 = cv.z; c3 = cv.w;
                    }
                    ax += v * c0;
                    ay += v * c1;
                    az += v * c2;
                    aw += v * c3;
                }
            }
            ax += __shfl_xor(ax, 16, 64); ax += __shfl_xor(ax, 32, 64);
            ay += __shfl_xor(ay, 16, 64); ay += __shfl_xor(ay, 32, 64);
            az += __shfl_xor(az, 16, 64); az += __shfl_xor(az, 32, 64);
            aw += __shfl_xor(aw, 16, 64); aw += __shfl_xor(aw, 32, 64);
            if (lane < 16) {
                float4 gf = ((float4*)useragg)[(size_t)u * 16 + qlane];
                ((float4*)useragg)[(size_t)u * 16 + qlane] =
                    make_float4(ax * (1.f + gf.x), ay * (1.f + gf.y),
                                az * (1.f + gf.z), aw * (1.f + gf.w));
            }
        }
    }
}

extern "C" void kernel_launch(void* const* d_in, const int* in_sizes, int n_in,
                              void* d_out, int out_size, void* d_ws, size_t ws_size,
                              hipStream_t stream) {
    const float* cat    = (const float*)d_in[0];
    const float* uemb   = (const float*)d_in[1];
    const int*   eidx   = (const int*)d_in[2];
    const int*   etype  = (const int*)d_in[3];
    const int*   iidx   = (const int*)d_in[4];
    const float* ival   = (const float*)d_in[5];
    const float* weight = (const float*)d_in[6];

    float* catagg  = (float*)d_out;
    float* useragg = (float*)d_out + (size_t)N_CAT * DIM;

    // workspace layout (4-byte words)
    int* ws = (int*)d_ws;
    float* normsq   = (float*)ws;                              // [0, 1.5M)
    int*   ebinned  = ws + 1500000;                            // [1.5M, 3M)
    unsigned long long* nbinned = (unsigned long long*)(ws + 3000000); // [3M, 6M)
    int*   gcnt     = ws + 6000000;                            // 1425
    int*   hbase    = ws + 6001425;                            // 801
    int*   ubase    = ws + 6002226;                            // 626
    int*   cur      = ws + 6002852;                            // 1425
    unsigned short* cat16 = (unsigned short*)(ws + 6004278);   // 6.4M ushorts
    const size_t NEED16 = (size_t)(6004278 + 3200000) * 4;
    bool use16 = ws_size >= NEED16;

    const int* head = eidx;
    const int* tail = eidx + E_EDGES;
    const int* iu   = iidx;
    const int* ic   = iidx + NNZ_E;

    hipMemsetAsync(gcnt, 0, (size_t)NB_T * sizeof(int), stream);

    if (use16) {
        prep_kernel<true><<<NS_TILES + GT_TILES + HIST_BLKS, 256, 0, stream>>>(
            cat, uemb, weight, head, iu, normsq, cat16, useragg, gcnt);
    } else {
        prep_kernel<false><<<NS_TILES + GT_TILES + HIST_BLKS, 256, 0, stream>>>(
            cat, uemb, weight, head, iu, normsq, cat16, useragg, gcnt);
    }
    bscan_kernel<<<1, 1024, 0, stream>>>(gcnt, hbase, ubase, cur);
    binning_kernel<<<BIN_BLKS, 1024, 0, stream>>>(head, tail, etype, iu, ic, ival,
                                                  cur, ebinned, nbinned);
    if (use16) {
        fused_agg<true><<<NB_T, 512, 0, stream>>>(
            ebinned, hbase, nbinned, ubase, normsq, cat, cat16, weight, catagg, useragg);
    } else {
        fused_agg<false><<<NB_T, 512, 0, stream>>>(
            ebinned, hbase, nbinned, ubase, normsq, cat, cat16, weight, catagg, useragg);
    }
}